// Round 10
// baseline (1450.371 us; speedup 1.0000x reference)
//
#include <hip/hip_runtime.h>

#define NB 16  // src buckets: edges of each dst are stored bucket-sorted

typedef float f32x2 __attribute__((ext_vector_type(2)));

// ---------- node GEMM: Y[N,M] = X[N,K] @ W[K,M] + b ----------
template <int K, int M>
__global__ __launch_bounds__(256) void node_gemm(
    const float* __restrict__ X, const float* __restrict__ W,
    const float* __restrict__ bias, float* __restrict__ Y) {
  constexpr int NPB = 16;
  constexpr int COLS4 = M / 4;
  constexpr int NG = 256 / COLS4;
  constexpr int RPN = NPB / NG;
  __shared__ float xs[NPB * K];
  const int tid = threadIdx.x;
  const int n0 = blockIdx.x * NPB;
  {
    const float4* X4 = reinterpret_cast<const float4*>(X + (size_t)n0 * K);
    float4* xs4 = reinterpret_cast<float4*>(xs);
    for (int i = tid; i < NPB * K / 4; i += 256) xs4[i] = X4[i];
  }
  __syncthreads();
  const int c4 = (tid % COLS4) * 4;
  const int r0 = (tid / COLS4) * RPN;
  float acc[RPN][4];
#pragma unroll
  for (int r = 0; r < RPN; ++r)
#pragma unroll
    for (int q = 0; q < 4; ++q) acc[r][q] = 0.f;

  for (int k = 0; k < K; k += 4) {
    float xv[RPN][4];
#pragma unroll
    for (int r = 0; r < RPN; ++r)
      *reinterpret_cast<float4*>(xv[r]) =
          *reinterpret_cast<const float4*>(&xs[(r0 + r) * K + k]);
#pragma unroll
    for (int j = 0; j < 4; ++j) {
      float wv[4];
      *reinterpret_cast<float4*>(wv) =
          *reinterpret_cast<const float4*>(&W[(size_t)(k + j) * M + c4]);
#pragma unroll
      for (int r = 0; r < RPN; ++r)
#pragma unroll
        for (int q = 0; q < 4; ++q)
          acc[r][q] = fmaf(xv[r][j], wv[q], acc[r][q]);
    }
  }
  float bv[4];
  *reinterpret_cast<float4*>(bv) = *reinterpret_cast<const float4*>(&bias[c4]);
#pragma unroll
  for (int r = 0; r < RPN; ++r) {
    float o[4];
#pragma unroll
    for (int q = 0; q < 4; ++q) o[q] = acc[r][q] + bv[q];
    *reinterpret_cast<float4*>(&Y[(size_t)(n0 + r0 + r) * M + c4]) =
        *reinterpret_cast<float4*>(o);
  }
}

// ---------- bucketed CSR build: key = dst*NB + src/bdiv ----------
__global__ void hist_b(const int* __restrict__ ei, int* __restrict__ kcnt,
                       int E, int bdiv) {
  int i = blockIdx.x * blockDim.x + threadIdx.x;
  if (i < E) atomicAdd(&kcnt[ei[E + i] * NB + ei[i] / bdiv], 1);
}

__global__ __launch_bounds__(1024) void blk_scan(
    const int* __restrict__ in, int* __restrict__ out1, int* __restrict__ bsum, int n) {
  __shared__ int buf[1024];
  const int tid = threadIdx.x;
  const int gid = blockIdx.x * 1024 + tid;
  int v = (gid < n) ? in[gid] : 0;
  buf[tid] = v;
  __syncthreads();
  for (int off = 1; off < 1024; off <<= 1) {
    int t = (tid >= off) ? buf[tid - off] : 0;
    __syncthreads();
    buf[tid] += t;
    __syncthreads();
  }
  if (gid < n) out1[gid] = buf[tid];
  if (tid == 1023) bsum[blockIdx.x] = buf[1023];
}

// one-block LDS inclusive scan of the per-block sums (nb <= 1024)
__global__ __launch_bounds__(1024) void scan_bsum(int* __restrict__ bsum, int nb) {
  __shared__ int buf[1024];
  const int tid = threadIdx.x;
  int v = (tid < nb) ? bsum[tid] : 0;
  buf[tid] = v;
  __syncthreads();
  for (int off = 1; off < 1024; off <<= 1) {
    int t = (tid >= off) ? buf[tid - off] : 0;
    __syncthreads();
    buf[tid] += t;
    __syncthreads();
  }
  if (tid < nb) bsum[tid] = buf[tid];
}

__global__ void add_off(int* __restrict__ kptr, const int* __restrict__ bsum, int n) {
  int gid = blockIdx.x * blockDim.x + threadIdx.x;
  if (gid == 0) kptr[0] = 0;
  if (gid < n) {
    int blk = gid >> 10;
    if (blk > 0) kptr[1 + gid] += bsum[blk - 1];
  }
}

__global__ void csr_fill_b(const int* __restrict__ ei, const int* __restrict__ kptr,
                           int* __restrict__ kfill, int* __restrict__ csr_src,
                           int* __restrict__ csr_eid, int E, int bdiv) {
  int i = blockIdx.x * blockDim.x + threadIdx.x;
  if (i < E) {
    int src = ei[i], dst = ei[E + i];
    int key = dst * NB + src / bdiv;
    int slot = kptr[key] + atomicAdd(&kfill[key], 1);
    csr_src[slot] = src;
    csr_eid[slot] = i;
  }
}

// permute edge_attr rows into CSR order (streamed scalar reads in the fused kernel)
__global__ void ea_perm(const float* __restrict__ ea, const int* __restrict__ csr_eid,
                        float* __restrict__ ea_csr, int E) {
  int i = blockIdx.x * blockDim.x + threadIdx.x;
  if (i < E * 16) {
    int slot = i >> 4;
    ea_csr[i] = ea[((size_t)csr_eid[slot] << 4) + (i & 15)];
  }
}

// ---------- graph boundary detection (batch is sorted) ----------
__global__ void graph_bounds(const int* __restrict__ batch, int* __restrict__ gstart,
                             int* __restrict__ gend, int N) {
  int i = blockIdx.x * blockDim.x + threadIdx.x;
  if (i < N) {
    int g = batch[i];
    atomicMin(&gstart[g], i);
    atomicMax(&gend[g], i + 1);
  }
}

// ---------- one edge of fused GATv2, packed-f32 FMA chain ----------
// c = 8 SGPR pairs holding the 16 ea coefficients; v_pk_fma_f32 op_sel
// broadcasts the lo (even k) or hi (odd k) scalar to both packed lanes.
template <int GS>
__device__ __forceinline__ void gat_edge_pk(
    const float4 a, const double (&c)[8], const float4 xrv,
    const f32x2 (&w01)[16], const f32x2 (&w23)[16], const float (&attv)[4],
    float& m, float& s, float (&acc)[4]) {
  f32x2 m01, m23;
  m01.x = a.x + xrv.x; m01.y = a.y + xrv.y;
  m23.x = a.z + xrv.z; m23.y = a.w + xrv.w;
#pragma unroll
  for (int i = 0; i < 8; ++i) {
    asm("v_pk_fma_f32 %0, %2, %3, %0 op_sel:[0,0,0] op_sel_hi:[0,1,1]\n\t"
        "v_pk_fma_f32 %1, %2, %4, %1 op_sel:[0,0,0] op_sel_hi:[0,1,1]\n\t"
        "v_pk_fma_f32 %0, %2, %5, %0 op_sel:[1,0,0] op_sel_hi:[1,1,1]\n\t"
        "v_pk_fma_f32 %1, %2, %6, %1 op_sel:[1,0,0] op_sel_hi:[1,1,1]"
        : "+v"(m01), "+v"(m23)
        : "s"(c[i]), "v"(w01[2 * i]), "v"(w23[2 * i]),
          "v"(w01[2 * i + 1]), "v"(w23[2 * i + 1]));
  }
  const float mv[4] = {m01.x, m01.y, m23.x, m23.y};
  float l = 0.f;
#pragma unroll
  for (int q = 0; q < 4; ++q) {
    const float v = fmaxf(mv[q], 0.2f * mv[q]);  // leaky-relu
    l = fmaf(v, attv[q], l);
  }
#pragma unroll
  for (int off = 1; off < GS; off <<= 1) l += __shfl_xor(l, off);
  const float nm = fmaxf(m, l);
  const float sc = __expf(m - nm);
  const float pe = __expf(l - nm);
  m = nm;
  s = fmaf(s, sc, pe);
  acc[0] = fmaf(pe, a.x, acc[0] * sc);
  acc[1] = fmaf(pe, a.y, acc[1] * sc);
  acc[2] = fmaf(pe, a.z, acc[2] * sc);
  acc[3] = fmaf(pe, a.w, acc[3] * sc);
}

// ---------- fused per-dst GATv2: 2 waves per dst (split edge list) ----------
// Block = 4 waves = 2 dsts x 2 edge-halves. Each wave runs the online-softmax
// over its contiguous half; partial (m,s,acc) merge through LDS.
// MODE 0: concat -> out[dst*HCROW + col0] = acc/s + bias  (grid = N/2)
// MODE 1: layer-2 head-pair partial mean; grid = N, halves interleaved by
//         (bx&1): even blocks cols 0..255 -> out, odd blocks cols 256..511 -> outB
template <int HCROW, int MODE>
__global__ __launch_bounds__(256) void fused_gat(
    const float* __restrict__ xl, const float* __restrict__ xr,
    const float* __restrict__ ea_csr, const float* __restrict__ We,
    const float* __restrict__ att, const float* __restrict__ bias,
    const int* __restrict__ kptr, const int* __restrict__ csr_src,
    float* __restrict__ out, float* __restrict__ outB, int N) {
  constexpr int C = HCROW / 4;   // per-head dim (64 or 128)
  constexpr int GS = C / 4;      // lanes per head group (16 or 32)
  __shared__ float mrg[2][64][6];  // 3 KB: partial state handoff
  const int lane = threadIdx.x & 63;
  const int wslot = threadIdx.x >> 6;
  const int dpair = wslot >> 1;  // which dst within the block
  const int half = wslot & 1;    // which edge half
  int bx = blockIdx.x;
  int colbase = 0;
  float* o_ptr = out;
  if (MODE == 1) {
    colbase = (bx & 1) * 256;
    if (bx & 1) o_ptr = outB;
    bx >>= 1;
  }
  const int dst = bx * 2 + dpair;  // N even -> always < N

  f32x2 w01[16], w23[16];
#pragma unroll
  for (int k = 0; k < 16; ++k) {
    const float4 t =
        *reinterpret_cast<const float4*>(&We[k * HCROW + colbase + lane * 4]);
    w01[k].x = t.x; w01[k].y = t.y;
    w23[k].x = t.z; w23[k].y = t.w;
  }
  const int col0 = colbase + lane * 4;
  const int head = col0 / C;
  float attv[4];
  *reinterpret_cast<float4*>(attv) =
      *reinterpret_cast<const float4*>(&att[head * C + (col0 % C)]);
  const float4* xl4 = reinterpret_cast<const float4*>(xl);
  const int rs4 = HCROW / 4;
  const int coff = col0 >> 2;
  const float4 xrv =
      reinterpret_cast<const float4*>(xr)[(size_t)dst * rs4 + coff];
  const double* ed = reinterpret_cast<const double*>(ea_csr);

  // wave-uniform full range, then this wave's half
  const int r0f = __builtin_amdgcn_readfirstlane(kptr[dst * NB]);
  const int rendf = __builtin_amdgcn_readfirstlane(kptr[dst * NB + NB]);
  const int mid = r0f + ((rendf - r0f + 1) >> 1);
  const int row0 = half ? mid : r0f;
  const int rend = half ? rendf : mid;

  float m = -__builtin_inff(), s = 0.f;
  float acc[4] = {0.f, 0.f, 0.f, 0.f};

  if (row0 < rend) {
    const int last = rend - 1;
    const int s0 = csr_src[row0];
    const int s1 = csr_src[min(row0 + 1, last)];
    const int s2 = csr_src[min(row0 + 2, last)];
    const int s3 = csr_src[min(row0 + 3, last)];
    float4 a0 = xl4[(size_t)s0 * rs4 + coff];
    float4 a1 = xl4[(size_t)s1 * rs4 + coff];
    float4 a2 = xl4[(size_t)s2 * rs4 + coff];
    float4 a3 = xl4[(size_t)s3 * rs4 + coff];
    int sr0 = csr_src[min(row0 + 4, last)];
    int sr1 = csr_src[min(row0 + 5, last)];
    double c0[8], c1[8];
    {
      const double* e0 = ed + (size_t)row0 * 8;
      const double* e1 = ed + (size_t)min(row0 + 1, last) * 8;
#pragma unroll
      for (int k = 0; k < 8; ++k) { c0[k] = e0[k]; c1[k] = e1[k]; }
    }

    for (int p = row0; p < rend; p += 2) {
      const float4 na0 = xl4[(size_t)sr0 * rs4 + coff];
      const float4 na1 = xl4[(size_t)sr1 * rs4 + coff];
      const int nsr0 = csr_src[min(p + 6, last)];
      const int nsr1 = csr_src[min(p + 7, last)];
      double cn0[8], cn1[8];
      {
        const double* e0 = ed + (size_t)min(p + 2, last) * 8;
        const double* e1 = ed + (size_t)min(p + 3, last) * 8;
#pragma unroll
        for (int k = 0; k < 8; ++k) { cn0[k] = e0[k]; cn1[k] = e1[k]; }
      }
      gat_edge_pk<GS>(a0, c0, xrv, w01, w23, attv, m, s, acc);
      if (p + 1 < rend) gat_edge_pk<GS>(a1, c1, xrv, w01, w23, attv, m, s, acc);
      a0 = a2; a1 = a3; a2 = na0; a3 = na1;
      sr0 = nsr0; sr1 = nsr1;
#pragma unroll
      for (int k = 0; k < 8; ++k) { c0[k] = cn0[k]; c1[k] = cn1[k]; }
    }
  }

  // ---- merge the two halves' states via LDS ----
  if (half) {
    mrg[dpair][lane][0] = m;
    mrg[dpair][lane][1] = s;
    mrg[dpair][lane][2] = acc[0];
    mrg[dpair][lane][3] = acc[1];
    mrg[dpair][lane][4] = acc[2];
    mrg[dpair][lane][5] = acc[3];
  }
  __syncthreads();
  if (half) return;
  {
    const float m1 = mrg[dpair][lane][0];
    const float s1 = mrg[dpair][lane][1];
    const float nm = fmaxf(m, m1);
    const float sc0 = (m > -1e37f) ? __expf(m - nm) : 0.f;
    const float sc1 = (m1 > -1e37f) ? __expf(m1 - nm) : 0.f;
    s = s * sc0 + s1 * sc1;
#pragma unroll
    for (int q = 0; q < 4; ++q)
      acc[q] = acc[q] * sc0 + mrg[dpair][lane][2 + q] * sc1;
  }

  const float inv = 1.f / (s + 1e-16f);
  float o[4];
  if (MODE == 0) {
    float bv[4];
    *reinterpret_cast<float4*>(bv) = *reinterpret_cast<const float4*>(&bias[col0]);
#pragma unroll
    for (int q = 0; q < 4; ++q) o[q] = fmaf(acc[q], inv, bv[q]);
    *reinterpret_cast<float4*>(&o_ptr[(size_t)dst * HCROW + col0]) =
        *reinterpret_cast<float4*>(o);
  } else {
#pragma unroll
    for (int q = 0; q < 4; ++q) {
      o[q] = acc[q] * inv;
      o[q] += __shfl_xor(o[q], 32);  // combine the slab's two heads
    }
    if (lane < 32)
      *reinterpret_cast<float4*>(&o_ptr[(size_t)dst * 128 + lane * 4]) =
          *reinterpret_cast<float4*>(o);
  }
}

// ---------- pooling: one block per graph, no atomics ----------
__global__ __launch_bounds__(256) void pool_graph(
    const float* __restrict__ hA, const float* __restrict__ hB,
    const float* __restrict__ bias2, const int* __restrict__ gstart,
    const int* __restrict__ gend, float* __restrict__ out) {
  const int g = blockIdx.x;
  const int c = threadIdx.x & 127;
  const int sub = threadIdx.x >> 7;
  const int s0 = gstart[g], e0 = gend[g];
  const float b = bias2[c];
  float mx = -__builtin_inff(), sm = 0.f;
  for (int n = s0 + sub; n < e0; n += 2) {
    const float v = fmaf(0.25f, hA[(size_t)n * 128 + c] + hB[(size_t)n * 128 + c], b);
    mx = fmaxf(mx, v);
    sm += v;
  }
  __shared__ float smx[128], ssm[128];
  if (sub) { smx[c] = mx; ssm[c] = sm; }
  __syncthreads();
  if (!sub) {
    mx = fmaxf(mx, smx[c]);
    sm += ssm[c];
    const int cnt = e0 - s0;
    out[g * 256 + c] = (cnt > 0) ? mx : 0.f;
    out[g * 256 + 128 + c] = sm / fmaxf((float)cnt, 1.f);
  }
}

extern "C" void kernel_launch(void* const* d_in, const int* in_sizes, int n_in,
                              void* d_out, int out_size, void* d_ws, size_t ws_size,
                              hipStream_t stream) {
  const float* x     = (const float*)d_in[0];
  const float* ea    = (const float*)d_in[1];
  const int*   ei    = (const int*)d_in[2];
  const int*   batch = (const int*)d_in[3];
  const int N = in_sizes[0] / 128;  // 20000
  const int E = in_sizes[2] / 2;    // 640000
  const int NBINS = N * NB;
  const int bdiv = (N + NB - 1) / NB;  // 1250

  const float* Wl[3]   = {(const float*)d_in[4],  (const float*)d_in[11], (const float*)d_in[18]};
  const float* blv[3]  = {(const float*)d_in[5],  (const float*)d_in[12], (const float*)d_in[19]};
  const float* Wr[3]   = {(const float*)d_in[6],  (const float*)d_in[13], (const float*)d_in[20]};
  const float* brv[3]  = {(const float*)d_in[7],  (const float*)d_in[14], (const float*)d_in[21]};
  const float* Wev[3]  = {(const float*)d_in[8],  (const float*)d_in[15], (const float*)d_in[22]};
  const float* attv[3] = {(const float*)d_in[9],  (const float*)d_in[16], (const float*)d_in[23]};
  const float* bias[3] = {(const float*)d_in[10], (const float*)d_in[17], (const float*)d_in[24]};

  // ---- workspace layout (floats) ----
  float* ws = (float*)d_ws;
  float* xl     = ws;                          // N*512
  float* xr     = xl + (size_t)N * 512;        // N*512
  float* ea_csr = xr + (size_t)N * 512;        // E*16
  float* h      = ea_csr + (size_t)E * 16;     // N*256 (aliased: build ints / hsumA,B)
  int* kptr     = (int*)(h + (size_t)N * 256); // NBINS+1
  int* csr_src  = kptr + (NBINS + 1);          // E
  int* bsum     = csr_src + E;                 // <=1024
  int* gstart   = bsum + 1024;                 // 64
  int* gend     = gstart + 64;                 // 64
  // build-time temps aliased inside h (dead before h is first written):
  int* csr_eid = (int*)h;                      // E
  int* kcnt    = csr_eid + E;                  // NBINS
  int* kfill   = kcnt + NBINS;                 // NBINS
  // layer-2 head-pair partial sums aliased inside h (h dead after L2 GEMMs):
  float* hsumA = h;                            // N*128
  float* hsumB = h + (size_t)N * 128;          // N*128
  (void)n_in; (void)out_size; (void)ws_size;

  const int nodeBlocks = N / 16;
  const int edgeBlocks = (E + 255) / 256;
  const int scanBlocks = (NBINS + 1023) / 1024;  // 313
  const int gatBlocks = N / 2;  // 4 waves/block = 2 dsts x 2 halves

  // ---- bucketed CSR build + graph bounds ----
  hipMemsetAsync(kcnt, 0, (size_t)2 * NBINS * sizeof(int), stream);  // kcnt+kfill
  hipMemsetAsync(gstart, 0x7f, 64 * sizeof(int), stream);            // ~INT_MAX
  hipMemsetAsync(gend, 0, 64 * sizeof(int), stream);
  hist_b<<<edgeBlocks, 256, 0, stream>>>(ei, kcnt, E, bdiv);
  graph_bounds<<<(N + 255) / 256, 256, 0, stream>>>(batch, gstart, gend, N);
  blk_scan<<<scanBlocks, 1024, 0, stream>>>(kcnt, kptr + 1, bsum, NBINS);
  scan_bsum<<<1, 1024, 0, stream>>>(bsum, scanBlocks);
  add_off<<<(NBINS + 255) / 256, 256, 0, stream>>>(kptr, bsum, NBINS);
  csr_fill_b<<<edgeBlocks, 256, 0, stream>>>(ei, kptr, kfill, csr_src, csr_eid, E, bdiv);
  ea_perm<<<(E * 16 + 255) / 256, 256, 0, stream>>>(ea, csr_eid, ea_csr, E);

  // ================= layer 0 (K=128 -> hc=256, concat) =================
  node_gemm<128, 256><<<nodeBlocks, 256, 0, stream>>>(x, Wl[0], blv[0], xl);
  node_gemm<128, 256><<<nodeBlocks, 256, 0, stream>>>(x, Wr[0], brv[0], xr);
  fused_gat<256, 0><<<gatBlocks, 256, 0, stream>>>(
      xl, xr, ea_csr, Wev[0], attv[0], bias[0], kptr, csr_src, h, nullptr, N);

  // ================= layer 1 (K=256 -> hc=256, concat) =================
  node_gemm<256, 256><<<nodeBlocks, 256, 0, stream>>>(h, Wl[1], blv[1], xl);
  node_gemm<256, 256><<<nodeBlocks, 256, 0, stream>>>(h, Wr[1], brv[1], xr);
  fused_gat<256, 0><<<gatBlocks, 256, 0, stream>>>(
      xl, xr, ea_csr, Wev[1], attv[1], bias[1], kptr, csr_src, h, nullptr, N);

  // ================= layer 2 (K=256 -> hc=512, mean over heads) =================
  node_gemm<256, 512><<<nodeBlocks, 256, 0, stream>>>(h, Wl[2], blv[2], xl);
  node_gemm<256, 512><<<nodeBlocks, 256, 0, stream>>>(h, Wr[2], brv[2], xr);
  fused_gat<512, 1><<<2 * gatBlocks, 256, 0, stream>>>(
      xl, xr, ea_csr, Wev[2], attv[2], bias[2], kptr, csr_src, hsumA, hsumB, N);

  // ================= pooling (mean-over-heads + bias fused, no atomics) ==========
  pool_graph<<<64, 256, 0, stream>>>(hsumA, hsumB, bias[2], gstart, gend, (float*)d_out);
}

// Round 11
// 1199.750 us; speedup vs baseline: 1.2089x; 1.2089x over previous
//
#include <hip/hip_runtime.h>

#define NB 32  // src buckets: edges of each dst are stored bucket-sorted

typedef float f32x2 __attribute__((ext_vector_type(2)));

// ---------- node GEMM: computes BOTH Y1 = X@W1+b1 and Y2 = X@W2+b2 ----------
// grid = 2*nodeBlocks; first half -> (W1,b1,Y1), second half -> (W2,b2,Y2)
template <int K, int M>
__global__ __launch_bounds__(256) void node_gemm2(
    const float* __restrict__ X, const float* __restrict__ W1,
    const float* __restrict__ b1, float* __restrict__ Y1,
    const float* __restrict__ W2, const float* __restrict__ b2,
    float* __restrict__ Y2, int nodeBlocks) {
  constexpr int NPB = 16;
  constexpr int COLS4 = M / 4;
  constexpr int NG = 256 / COLS4;
  constexpr int RPN = NPB / NG;
  __shared__ float xs[NPB * K];
  const int tid = threadIdx.x;
  const int hi = blockIdx.x >= nodeBlocks;
  const float* W = hi ? W2 : W1;
  const float* bias = hi ? b2 : b1;
  float* Y = hi ? Y2 : Y1;
  const int n0 = (hi ? blockIdx.x - nodeBlocks : blockIdx.x) * NPB;
  {
    const float4* X4 = reinterpret_cast<const float4*>(X + (size_t)n0 * K);
    float4* xs4 = reinterpret_cast<float4*>(xs);
    for (int i = tid; i < NPB * K / 4; i += 256) xs4[i] = X4[i];
  }
  __syncthreads();
  const int c4 = (tid % COLS4) * 4;
  const int r0 = (tid / COLS4) * RPN;
  float acc[RPN][4];
#pragma unroll
  for (int r = 0; r < RPN; ++r)
#pragma unroll
    for (int q = 0; q < 4; ++q) acc[r][q] = 0.f;

  for (int k = 0; k < K; k += 4) {
    float xv[RPN][4];
#pragma unroll
    for (int r = 0; r < RPN; ++r)
      *reinterpret_cast<float4*>(xv[r]) =
          *reinterpret_cast<const float4*>(&xs[(r0 + r) * K + k]);
#pragma unroll
    for (int j = 0; j < 4; ++j) {
      float wv[4];
      *reinterpret_cast<float4*>(wv) =
          *reinterpret_cast<const float4*>(&W[(size_t)(k + j) * M + c4]);
#pragma unroll
      for (int r = 0; r < RPN; ++r)
#pragma unroll
        for (int q = 0; q < 4; ++q)
          acc[r][q] = fmaf(xv[r][j], wv[q], acc[r][q]);
    }
  }
  float bv[4];
  *reinterpret_cast<float4*>(bv) = *reinterpret_cast<const float4*>(&bias[c4]);
#pragma unroll
  for (int r = 0; r < RPN; ++r) {
    float o[4];
#pragma unroll
    for (int q = 0; q < 4; ++q) o[q] = acc[r][q] + bv[q];
    *reinterpret_cast<float4*>(&Y[(size_t)(n0 + r0 + r) * M + c4]) =
        *reinterpret_cast<float4*>(o);
  }
}

// ---------- bucketed CSR build: key = dst*NB + src/bdiv ----------
__global__ void hist_b(const int* __restrict__ ei, int* __restrict__ kcnt,
                       int E, int bdiv) {
  int i = blockIdx.x * blockDim.x + threadIdx.x;
  if (i < E) atomicAdd(&kcnt[ei[E + i] * NB + ei[i] / bdiv], 1);
}

__global__ __launch_bounds__(1024) void blk_scan(
    const int* __restrict__ in, int* __restrict__ out1, int* __restrict__ bsum, int n) {
  __shared__ int buf[1024];
  const int tid = threadIdx.x;
  const int gid = blockIdx.x * 1024 + tid;
  int v = (gid < n) ? in[gid] : 0;
  buf[tid] = v;
  __syncthreads();
  for (int off = 1; off < 1024; off <<= 1) {
    int t = (tid >= off) ? buf[tid - off] : 0;
    __syncthreads();
    buf[tid] += t;
    __syncthreads();
  }
  if (gid < n) out1[gid] = buf[tid];
  if (tid == 1023) bsum[blockIdx.x] = buf[1023];
}

// one-block LDS inclusive scan of the per-block sums (nb <= 1024)
__global__ __launch_bounds__(1024) void scan_bsum(int* __restrict__ bsum, int nb) {
  __shared__ int buf[1024];
  const int tid = threadIdx.x;
  int v = (tid < nb) ? bsum[tid] : 0;
  buf[tid] = v;
  __syncthreads();
  for (int off = 1; off < 1024; off <<= 1) {
    int t = (tid >= off) ? buf[tid - off] : 0;
    __syncthreads();
    buf[tid] += t;
    __syncthreads();
  }
  if (tid < nb) bsum[tid] = buf[tid];
}

__global__ void add_off(int* __restrict__ kptr, const int* __restrict__ bsum, int n) {
  int gid = blockIdx.x * blockDim.x + threadIdx.x;
  if (gid == 0) kptr[0] = 0;
  if (gid < n) {
    int blk = gid >> 10;
    if (blk > 0) kptr[1 + gid] += bsum[blk - 1];
  }
}

__global__ void csr_fill_b(const int* __restrict__ ei, const int* __restrict__ kptr,
                           int* __restrict__ kfill, int* __restrict__ csr_src,
                           int* __restrict__ csr_eid, int E, int bdiv) {
  int i = blockIdx.x * blockDim.x + threadIdx.x;
  if (i < E) {
    int src = ei[i], dst = ei[E + i];
    int key = dst * NB + src / bdiv;
    int slot = kptr[key] + atomicAdd(&kfill[key], 1);
    csr_src[slot] = src;
    csr_eid[slot] = i;
  }
}

// permute edge_attr rows into CSR order (streamed scalar reads in the fused kernel)
__global__ void ea_perm(const float* __restrict__ ea, const int* __restrict__ csr_eid,
                        float* __restrict__ ea_csr, int E) {
  int i = blockIdx.x * blockDim.x + threadIdx.x;
  if (i < E * 16) {
    int slot = i >> 4;
    ea_csr[i] = ea[((size_t)csr_eid[slot] << 4) + (i & 15)];
  }
}

// ---------- graph boundary detection (batch is sorted) ----------
__global__ void graph_bounds(const int* __restrict__ batch, int* __restrict__ gstart,
                             int* __restrict__ gend, int N) {
  int i = blockIdx.x * blockDim.x + threadIdx.x;
  if (i < N) {
    int g = batch[i];
    atomicMin(&gstart[g], i);
    atomicMax(&gend[g], i + 1);
  }
}

// ---------- one edge of fused GATv2, packed-f32 FMA chain ----------
// c = 8 SGPR pairs holding the 16 ea coefficients; v_pk_fma_f32 op_sel
// broadcasts the lo (even k) or hi (odd k) scalar to both packed lanes.
template <int GS>
__device__ __forceinline__ void gat_edge_pk(
    const float4 a, const double (&c)[8], const float4 xrv,
    const f32x2 (&w01)[16], const f32x2 (&w23)[16], const float (&attv)[4],
    float& m, float& s, float (&acc)[4]) {
  f32x2 m01, m23;
  m01.x = a.x + xrv.x; m01.y = a.y + xrv.y;
  m23.x = a.z + xrv.z; m23.y = a.w + xrv.w;
#pragma unroll
  for (int i = 0; i < 8; ++i) {
    asm("v_pk_fma_f32 %0, %2, %3, %0 op_sel:[0,0,0] op_sel_hi:[0,1,1]\n\t"
        "v_pk_fma_f32 %1, %2, %4, %1 op_sel:[0,0,0] op_sel_hi:[0,1,1]\n\t"
        "v_pk_fma_f32 %0, %2, %5, %0 op_sel:[1,0,0] op_sel_hi:[1,1,1]\n\t"
        "v_pk_fma_f32 %1, %2, %6, %1 op_sel:[1,0,0] op_sel_hi:[1,1,1]"
        : "+v"(m01), "+v"(m23)
        : "s"(c[i]), "v"(w01[2 * i]), "v"(w23[2 * i]),
          "v"(w01[2 * i + 1]), "v"(w23[2 * i + 1]));
  }
  const float mv[4] = {m01.x, m01.y, m23.x, m23.y};
  float l = 0.f;
#pragma unroll
  for (int q = 0; q < 4; ++q) {
    const float v = fmaxf(mv[q], 0.2f * mv[q]);  // leaky-relu
    l = fmaf(v, attv[q], l);
  }
#pragma unroll
  for (int off = 1; off < GS; off <<= 1) l += __shfl_xor(l, off);
  const float nm = fmaxf(m, l);
  const float sc = __expf(m - nm);
  const float pe = __expf(l - nm);
  m = nm;
  s = fmaf(s, sc, pe);
  acc[0] = fmaf(pe, a.x, acc[0] * sc);
  acc[1] = fmaf(pe, a.y, acc[1] * sc);
  acc[2] = fmaf(pe, a.z, acc[2] * sc);
  acc[3] = fmaf(pe, a.w, acc[3] * sc);
}

// ---------- fused per-dst GATv2: wave-per-dst, 8-deep gather ring ----------
// One wave owns one dst (256-column slab). Edge metadata via scalar loads;
// xl rows gathered with an 8-row ring (2 issued per 2-edge iteration).
// MODE 0: concat -> out[dst*HCROW + col0] = acc/s + bias  (grid = N/4)
// MODE 1: layer-2 head-pair partial mean; grid = N/2, halves interleaved by
//         (bx&1): even blocks cols 0..255 -> out, odd blocks cols 256..511 -> outB
template <int HCROW, int MODE>
__global__ __launch_bounds__(256) void fused_gat(
    const float* __restrict__ xl, const float* __restrict__ xr,
    const float* __restrict__ ea_csr, const float* __restrict__ We,
    const float* __restrict__ att, const float* __restrict__ bias,
    const int* __restrict__ kptr, const int* __restrict__ csr_src,
    float* __restrict__ out, float* __restrict__ outB, int N) {
  constexpr int C = HCROW / 4;   // per-head dim (64 or 128)
  constexpr int GS = C / 4;      // lanes per head group (16 or 32)
  const int lane = threadIdx.x & 63;
  const int wslot = threadIdx.x >> 6;
  int bx = blockIdx.x;
  int colbase = 0;
  float* o_ptr = out;
  if (MODE == 1) {
    colbase = (bx & 1) * 256;
    if (bx & 1) o_ptr = outB;
    bx >>= 1;
  }
  const int dst = bx * 4 + wslot;
  if (dst >= N) return;

  f32x2 w01[16], w23[16];
#pragma unroll
  for (int k = 0; k < 16; ++k) {
    const float4 t =
        *reinterpret_cast<const float4*>(&We[k * HCROW + colbase + lane * 4]);
    w01[k].x = t.x; w01[k].y = t.y;
    w23[k].x = t.z; w23[k].y = t.w;
  }
  const int col0 = colbase + lane * 4;
  const int head = col0 / C;
  float attv[4];
  *reinterpret_cast<float4*>(attv) =
      *reinterpret_cast<const float4*>(&att[head * C + (col0 % C)]);
  const float4* xl4 = reinterpret_cast<const float4*>(xl);
  const int rs4 = HCROW / 4;
  const int coff = col0 >> 2;
  const float4 xrv =
      reinterpret_cast<const float4*>(xr)[(size_t)dst * rs4 + coff];
  const double* ed = reinterpret_cast<const double*>(ea_csr);

  // wave-uniform row range (readfirstlane anchors uniformity -> s_load chain)
  const int row0 = __builtin_amdgcn_readfirstlane(kptr[dst * NB]);
  const int rend = __builtin_amdgcn_readfirstlane(kptr[dst * NB + NB]);

  float m = -__builtin_inff(), s = 0.f;
  float acc[4] = {0.f, 0.f, 0.f, 0.f};

  if (row0 < rend) {
    const int last = rend - 1;
    // ---- prologue: prime 8-row ring ----
    int sp[8];
#pragma unroll
    for (int i = 0; i < 8; ++i) sp[i] = csr_src[min(row0 + i, last)];
    float4 a0 = xl4[(size_t)sp[0] * rs4 + coff];
    float4 a1 = xl4[(size_t)sp[1] * rs4 + coff];
    float4 a2 = xl4[(size_t)sp[2] * rs4 + coff];
    float4 a3 = xl4[(size_t)sp[3] * rs4 + coff];
    float4 a4 = xl4[(size_t)sp[4] * rs4 + coff];
    float4 a5 = xl4[(size_t)sp[5] * rs4 + coff];
    float4 a6 = xl4[(size_t)sp[6] * rs4 + coff];
    float4 a7 = xl4[(size_t)sp[7] * rs4 + coff];
    int sr0 = csr_src[min(row0 + 8, last)];
    int sr1 = csr_src[min(row0 + 9, last)];
    double c0[8], c1[8];
    {
      const double* e0 = ed + (size_t)row0 * 8;
      const double* e1 = ed + (size_t)min(row0 + 1, last) * 8;
#pragma unroll
      for (int k = 0; k < 8; ++k) { c0[k] = e0[k]; c1[k] = e1[k]; }
    }

    for (int p = row0; p < rend; p += 2) {
      // issue gathers for p+8/p+9 (src ids already resident -> no addr wait)
      const float4 na0 = xl4[(size_t)sr0 * rs4 + coff];
      const float4 na1 = xl4[(size_t)sr1 * rs4 + coff];
      // scalar loads: srcs for p+10/p+11, ea rows for p+2/p+3
      const int nsr0 = csr_src[min(p + 10, last)];
      const int nsr1 = csr_src[min(p + 11, last)];
      double cn0[8], cn1[8];
      {
        const double* e0 = ed + (size_t)min(p + 2, last) * 8;
        const double* e1 = ed + (size_t)min(p + 3, last) * 8;
#pragma unroll
        for (int k = 0; k < 8; ++k) { cn0[k] = e0[k]; cn1[k] = e1[k]; }
      }
      // compute edges p, p+1 (rows loaded 4 iterations ago)
      gat_edge_pk<GS>(a0, c0, xrv, w01, w23, attv, m, s, acc);
      if (p + 1 < rend) gat_edge_pk<GS>(a1, c1, xrv, w01, w23, attv, m, s, acc);
      // rotate ring
      a0 = a2; a1 = a3; a2 = a4; a3 = a5; a4 = a6; a5 = a7; a6 = na0; a7 = na1;
      sr0 = nsr0; sr1 = nsr1;
#pragma unroll
      for (int k = 0; k < 8; ++k) { c0[k] = cn0[k]; c1[k] = cn1[k]; }
    }
  }

  const float inv = 1.f / (s + 1e-16f);
  float o[4];
  if (MODE == 0) {
    float bv[4];
    *reinterpret_cast<float4*>(bv) = *reinterpret_cast<const float4*>(&bias[col0]);
#pragma unroll
    for (int q = 0; q < 4; ++q) o[q] = fmaf(acc[q], inv, bv[q]);
    *reinterpret_cast<float4*>(&o_ptr[(size_t)dst * HCROW + col0]) =
        *reinterpret_cast<float4*>(o);
  } else {
#pragma unroll
    for (int q = 0; q < 4; ++q) {
      o[q] = acc[q] * inv;
      o[q] += __shfl_xor(o[q], 32);  // combine the slab's two heads
    }
    if (lane < 32)
      *reinterpret_cast<float4*>(&o_ptr[(size_t)dst * 128 + lane * 4]) =
          *reinterpret_cast<float4*>(o);
  }
}

// ---------- pooling: one block per graph, no atomics ----------
__global__ __launch_bounds__(256) void pool_graph(
    const float* __restrict__ hA, const float* __restrict__ hB,
    const float* __restrict__ bias2, const int* __restrict__ gstart,
    const int* __restrict__ gend, float* __restrict__ out) {
  const int g = blockIdx.x;
  const int c = threadIdx.x & 127;
  const int sub = threadIdx.x >> 7;
  const int s0 = gstart[g], e0 = gend[g];
  const float b = bias2[c];
  float mx = -__builtin_inff(), sm = 0.f;
  for (int n = s0 + sub; n < e0; n += 2) {
    const float v = fmaf(0.25f, hA[(size_t)n * 128 + c] + hB[(size_t)n * 128 + c], b);
    mx = fmaxf(mx, v);
    sm += v;
  }
  __shared__ float smx[128], ssm[128];
  if (sub) { smx[c] = mx; ssm[c] = sm; }
  __syncthreads();
  if (!sub) {
    mx = fmaxf(mx, smx[c]);
    sm += ssm[c];
    const int cnt = e0 - s0;
    out[g * 256 + c] = (cnt > 0) ? mx : 0.f;
    out[g * 256 + 128 + c] = sm / fmaxf((float)cnt, 1.f);
  }
}

extern "C" void kernel_launch(void* const* d_in, const int* in_sizes, int n_in,
                              void* d_out, int out_size, void* d_ws, size_t ws_size,
                              hipStream_t stream) {
  const float* x     = (const float*)d_in[0];
  const float* ea    = (const float*)d_in[1];
  const int*   ei    = (const int*)d_in[2];
  const int*   batch = (const int*)d_in[3];
  const int N = in_sizes[0] / 128;  // 20000
  const int E = in_sizes[2] / 2;    // 640000
  const int NBINS = N * NB;
  const int bdiv = (N + NB - 1) / NB;  // 626

  const float* Wl[3]   = {(const float*)d_in[4],  (const float*)d_in[11], (const float*)d_in[18]};
  const float* blv[3]  = {(const float*)d_in[5],  (const float*)d_in[12], (const float*)d_in[19]};
  const float* Wr[3]   = {(const float*)d_in[6],  (const float*)d_in[13], (const float*)d_in[20]};
  const float* brv[3]  = {(const float*)d_in[7],  (const float*)d_in[14], (const float*)d_in[21]};
  const float* Wev[3]  = {(const float*)d_in[8],  (const float*)d_in[15], (const float*)d_in[22]};
  const float* attv[3] = {(const float*)d_in[9],  (const float*)d_in[16], (const float*)d_in[23]};
  const float* bias[3] = {(const float*)d_in[10], (const float*)d_in[17], (const float*)d_in[24]};

  // ---- workspace layout (floats) ----
  float* ws = (float*)d_ws;
  float* xl     = ws;                          // N*512
  float* xr     = xl + (size_t)N * 512;        // N*512
  float* ea_csr = xr + (size_t)N * 512;        // E*16
  float* h      = ea_csr + (size_t)E * 16;     // N*256 (aliased: build ints / hsumA,B)
  int* kptr     = (int*)(h + (size_t)N * 256); // NBINS+1
  int* csr_src  = kptr + (NBINS + 1);          // E
  int* bsum     = csr_src + E;                 // <=1024
  int* gstart   = bsum + 1024;                 // 64
  int* gend     = gstart + 64;                 // 64
  // build-time temps aliased inside h (dead before h is first written):
  int* csr_eid = (int*)h;                      // E
  int* kcnt    = csr_eid + E;                  // NBINS
  int* kfill   = kcnt + NBINS;                 // NBINS
  // layer-2 head-pair partial sums aliased inside h (h dead after L2 GEMMs):
  float* hsumA = h;                            // N*128
  float* hsumB = h + (size_t)N * 128;          // N*128
  (void)n_in; (void)out_size; (void)ws_size;

  const int nodeBlocks = N / 16;
  const int edgeBlocks = (E + 255) / 256;
  const int scanBlocks = (NBINS + 1023) / 1024;  // 625
  const int gatBlocks = (N + 3) / 4;  // 4 waves/block, wave-per-dst

  // ---- bucketed CSR build + graph bounds ----
  hipMemsetAsync(kcnt, 0, (size_t)2 * NBINS * sizeof(int), stream);  // kcnt+kfill
  hipMemsetAsync(gstart, 0x7f, 64 * sizeof(int), stream);            // ~INT_MAX
  hipMemsetAsync(gend, 0, 64 * sizeof(int), stream);
  hist_b<<<edgeBlocks, 256, 0, stream>>>(ei, kcnt, E, bdiv);
  graph_bounds<<<(N + 255) / 256, 256, 0, stream>>>(batch, gstart, gend, N);
  blk_scan<<<scanBlocks, 1024, 0, stream>>>(kcnt, kptr + 1, bsum, NBINS);
  scan_bsum<<<1, 1024, 0, stream>>>(bsum, scanBlocks);
  add_off<<<(NBINS + 255) / 256, 256, 0, stream>>>(kptr, bsum, NBINS);
  csr_fill_b<<<edgeBlocks, 256, 0, stream>>>(ei, kptr, kfill, csr_src, csr_eid, E, bdiv);
  ea_perm<<<(E * 16 + 255) / 256, 256, 0, stream>>>(ea, csr_eid, ea_csr, E);

  // ================= layer 0 (K=128 -> hc=256, concat) =================
  node_gemm2<128, 256><<<2 * nodeBlocks, 256, 0, stream>>>(
      x, Wl[0], blv[0], xl, Wr[0], brv[0], xr, nodeBlocks);
  fused_gat<256, 0><<<gatBlocks, 256, 0, stream>>>(
      xl, xr, ea_csr, Wev[0], attv[0], bias[0], kptr, csr_src, h, nullptr, N);

  // ================= layer 1 (K=256 -> hc=256, concat) =================
  node_gemm2<256, 256><<<2 * nodeBlocks, 256, 0, stream>>>(
      h, Wl[1], blv[1], xl, Wr[1], brv[1], xr, nodeBlocks);
  fused_gat<256, 0><<<gatBlocks, 256, 0, stream>>>(
      xl, xr, ea_csr, Wev[1], attv[1], bias[1], kptr, csr_src, h, nullptr, N);

  // ================= layer 2 (K=256 -> hc=512, mean over heads) =================
  node_gemm2<256, 512><<<2 * nodeBlocks, 256, 0, stream>>>(
      h, Wl[2], blv[2], xl, Wr[2], brv[2], xr, nodeBlocks);
  fused_gat<512, 1><<<2 * gatBlocks, 256, 0, stream>>>(
      xl, xr, ea_csr, Wev[2], attv[2], bias[2], kptr, csr_src, hsumA, hsumB, N);

  // ================= pooling (mean-over-heads + bias fused, no atomics) ==========
  pool_graph<<<64, 256, 0, stream>>>(hsumA, hsumB, bias[2], gstart, gend, (float*)d_out);
}

// Round 12
// 1041.569 us; speedup vs baseline: 1.3925x; 1.1519x over previous
//
#include <hip/hip_runtime.h>

#define NB 8  // src buckets: edges of each dst are stored bucket-sorted

// ---------- node GEMM: computes BOTH Y1 = X@W1+b1 and Y2 = X@W2+b2 ----------
// grid = 2*nodeBlocks; first half -> (W1,b1,Y1), second half -> (W2,b2,Y2)
template <int K, int M>
__global__ __launch_bounds__(256) void node_gemm2(
    const float* __restrict__ X, const float* __restrict__ W1,
    const float* __restrict__ b1, float* __restrict__ Y1,
    const float* __restrict__ W2, const float* __restrict__ b2,
    float* __restrict__ Y2, int nodeBlocks) {
  constexpr int NPB = 16;
  constexpr int COLS4 = M / 4;
  constexpr int NG = 256 / COLS4;
  constexpr int RPN = NPB / NG;
  __shared__ float xs[NPB * K];
  const int tid = threadIdx.x;
  const int hi = blockIdx.x >= nodeBlocks;
  const float* W = hi ? W2 : W1;
  const float* bias = hi ? b2 : b1;
  float* Y = hi ? Y2 : Y1;
  const int n0 = (hi ? blockIdx.x - nodeBlocks : blockIdx.x) * NPB;
  {
    const float4* X4 = reinterpret_cast<const float4*>(X + (size_t)n0 * K);
    float4* xs4 = reinterpret_cast<float4*>(xs);
    for (int i = tid; i < NPB * K / 4; i += 256) xs4[i] = X4[i];
  }
  __syncthreads();
  const int c4 = (tid % COLS4) * 4;
  const int r0 = (tid / COLS4) * RPN;
  float acc[RPN][4];
#pragma unroll
  for (int r = 0; r < RPN; ++r)
#pragma unroll
    for (int q = 0; q < 4; ++q) acc[r][q] = 0.f;

  for (int k = 0; k < K; k += 4) {
    float xv[RPN][4];
#pragma unroll
    for (int r = 0; r < RPN; ++r)
      *reinterpret_cast<float4*>(xv[r]) =
          *reinterpret_cast<const float4*>(&xs[(r0 + r) * K + k]);
#pragma unroll
    for (int j = 0; j < 4; ++j) {
      float wv[4];
      *reinterpret_cast<float4*>(wv) =
          *reinterpret_cast<const float4*>(&W[(size_t)(k + j) * M + c4]);
#pragma unroll
      for (int r = 0; r < RPN; ++r)
#pragma unroll
        for (int q = 0; q < 4; ++q)
          acc[r][q] = fmaf(xv[r][j], wv[q], acc[r][q]);
    }
  }
  float bv[4];
  *reinterpret_cast<float4*>(bv) = *reinterpret_cast<const float4*>(&bias[c4]);
#pragma unroll
  for (int r = 0; r < RPN; ++r) {
    float o[4];
#pragma unroll
    for (int q = 0; q < 4; ++q) o[q] = acc[r][q] + bv[q];
    *reinterpret_cast<float4*>(&Y[(size_t)(n0 + r0 + r) * M + c4]) =
        *reinterpret_cast<float4*>(o);
  }
}

// ---------- bucketed CSR build: key = dst*NB + src/bdiv ----------
// also computes per-graph node bounds (batch is sorted)
__global__ void hist_b(const int* __restrict__ ei, int* __restrict__ kcnt,
                       const int* __restrict__ batch, int* __restrict__ gstart,
                       int* __restrict__ gend, int E, int N, int bdiv) {
  int i = blockIdx.x * blockDim.x + threadIdx.x;
  if (i < E) atomicAdd(&kcnt[ei[E + i] * NB + ei[i] / bdiv], 1);
  if (i < N) {
    int g = batch[i];
    atomicMin(&gstart[g], i);
    atomicMax(&gend[g], i + 1);
  }
}

__global__ __launch_bounds__(1024) void blk_scan(
    const int* __restrict__ in, int* __restrict__ out1, int* __restrict__ bsum, int n) {
  __shared__ int buf[1024];
  const int tid = threadIdx.x;
  const int gid = blockIdx.x * 1024 + tid;
  int v = (gid < n) ? in[gid] : 0;
  buf[tid] = v;
  __syncthreads();
  for (int off = 1; off < 1024; off <<= 1) {
    int t = (tid >= off) ? buf[tid - off] : 0;
    __syncthreads();
    buf[tid] += t;
    __syncthreads();
  }
  if (gid < n) out1[gid] = buf[tid];
  if (tid == 1023) bsum[blockIdx.x] = buf[1023];
}

// one-block LDS inclusive scan of the per-block sums (nb <= 256)
__global__ __launch_bounds__(256) void scan_bsum(int* __restrict__ bsum, int nb) {
  __shared__ int buf[256];
  const int tid = threadIdx.x;
  int v = (tid < nb) ? bsum[tid] : 0;
  buf[tid] = v;
  __syncthreads();
  for (int off = 1; off < 256; off <<= 1) {
    int t = (tid >= off) ? buf[tid - off] : 0;
    __syncthreads();
    buf[tid] += t;
    __syncthreads();
  }
  if (tid < nb) bsum[tid] = buf[tid];
}

__global__ void add_off(int* __restrict__ kptr, const int* __restrict__ bsum, int n) {
  int gid = blockIdx.x * blockDim.x + threadIdx.x;
  if (gid == 0) kptr[0] = 0;
  if (gid < n) {
    int blk = gid >> 10;
    if (blk > 0) kptr[1 + gid] += bsum[blk - 1];
  }
}

// fill CSR src ids AND scatter edge_attr rows into CSR order in the same pass
// (ea read is streaming/coalesced: thread i reads ea[i*16..i*16+15])
__global__ void csr_fill_b(const int* __restrict__ ei, const int* __restrict__ kptr,
                           int* __restrict__ kfill, int* __restrict__ csr_src,
                           const float* __restrict__ ea, float* __restrict__ ea_csr,
                           int E, int bdiv) {
  int i = blockIdx.x * blockDim.x + threadIdx.x;
  if (i < E) {
    int src = ei[i], dst = ei[E + i];
    int key = dst * NB + src / bdiv;
    int slot = kptr[key] + atomicAdd(&kfill[key], 1);
    csr_src[slot] = src;
    const float4* es = reinterpret_cast<const float4*>(ea) + (size_t)i * 4;
    float4* ed = reinterpret_cast<float4*>(ea_csr) + (size_t)slot * 4;
    float4 v0 = es[0], v1 = es[1], v2 = es[2], v3 = es[3];
    ed[0] = v0; ed[1] = v1; ed[2] = v2; ed[3] = v3;
  }
}

// ---------- one edge of fused GATv2 with SGPR-resident ea coefficients ----------
template <int GS>
__device__ __forceinline__ void gat_edge_s(
    const float4 a, const float (&c)[16], const float4 xv,
    const float (&wef)[16][4], const float (&attv)[4],
    float& m, float& s, float (&acc)[4]) {
  float mv[4] = {a.x + xv.x, a.y + xv.y, a.z + xv.z, a.w + xv.w};
#pragma unroll
  for (int k = 0; k < 16; ++k) {
#pragma unroll
    for (int q = 0; q < 4; ++q) mv[q] = fmaf(c[k], wef[k][q], mv[q]);
  }
  float l = 0.f;
#pragma unroll
  for (int q = 0; q < 4; ++q) {
    const float v = fmaxf(mv[q], 0.2f * mv[q]);  // leaky-relu
    l = fmaf(v, attv[q], l);
  }
#pragma unroll
  for (int off = 1; off < GS; off <<= 1) l += __shfl_xor(l, off);
  const float nm = fmaxf(m, l);
  const float sc = __expf(m - nm);
  const float pe = __expf(l - nm);
  m = nm;
  s = fmaf(s, sc, pe);
  acc[0] = fmaf(pe, a.x, acc[0] * sc);
  acc[1] = fmaf(pe, a.y, acc[1] * sc);
  acc[2] = fmaf(pe, a.z, acc[2] * sc);
  acc[3] = fmaf(pe, a.w, acc[3] * sc);
}

// ---------- fused per-dst GATv2: wave-per-dst, scalar edge metadata ----------
// One wave owns one dst (256-column slab). Edge index p, src id, and the
// 16-float ea row are wave-uniform -> scalar loads (s_load), SGPR operands in
// the FMA chain. Gather pipeline: 4 xl rows in flight.
// MODE 0: concat -> out[dst*HCROW + col0] = acc/s + bias  (grid = gb)
// MODE 1: layer-2 head-pair partial mean; grid = 2*gb: first half writes out
//         (cols 0..255, heads 0/1), second half outB (cols 256..511, heads 2/3)
template <int HCROW, int MODE>
__global__ __launch_bounds__(256) void fused_gat(
    const float* __restrict__ xl, const float* __restrict__ xr,
    const float* __restrict__ ea_csr, const float* __restrict__ We,
    const float* __restrict__ att, const float* __restrict__ bias,
    const int* __restrict__ kptr, const int* __restrict__ csr_src,
    float* __restrict__ out, float* __restrict__ outB, int N) {
  constexpr int C = HCROW / 4;   // per-head dim (64 or 128)
  constexpr int GS = C / 4;      // lanes per head group (16 or 32)
  const int lane = threadIdx.x & 63;
  const int wslot = threadIdx.x >> 6;
  int bx = blockIdx.x;
  int colbase = 0;
  float* o_ptr = out;
  if (MODE == 1) {
    const int gb = gridDim.x >> 1;
    if (bx >= gb) { bx -= gb; colbase = 256; o_ptr = outB; }
  }
  const int dst = bx * 4 + wslot;
  if (dst >= N) return;

  float wef[16][4];
#pragma unroll
  for (int k = 0; k < 16; ++k)
    *reinterpret_cast<float4*>(wef[k]) =
        *reinterpret_cast<const float4*>(&We[k * HCROW + colbase + lane * 4]);
  const int col0 = colbase + lane * 4;
  const int head = col0 / C;
  float attv[4];
  *reinterpret_cast<float4*>(attv) =
      *reinterpret_cast<const float4*>(&att[head * C + (col0 % C)]);
  const float4* xl4 = reinterpret_cast<const float4*>(xl);
  const int rs4 = HCROW / 4;
  const int coff = col0 >> 2;
  const float4 xrv =
      reinterpret_cast<const float4*>(xr)[(size_t)dst * rs4 + coff];

  // wave-uniform row range (readfirstlane anchors uniformity -> s_load chain)
  const int row0 = __builtin_amdgcn_readfirstlane(kptr[dst * NB]);
  const int rend = __builtin_amdgcn_readfirstlane(kptr[dst * NB + NB]);

  float m = -__builtin_inff(), s = 0.f;
  float acc[4] = {0.f, 0.f, 0.f, 0.f};

  if (row0 < rend) {
    const int last = rend - 1;
    // prologue: 4 gather rows in flight, current ea pair, src pair for p+4/5
    const int s0 = csr_src[row0];
    const int s1 = csr_src[min(row0 + 1, last)];
    const int s2 = csr_src[min(row0 + 2, last)];
    const int s3 = csr_src[min(row0 + 3, last)];
    float4 a0 = xl4[(size_t)s0 * rs4 + coff];
    float4 a1 = xl4[(size_t)s1 * rs4 + coff];
    float4 a2 = xl4[(size_t)s2 * rs4 + coff];
    float4 a3 = xl4[(size_t)s3 * rs4 + coff];
    int sr0 = csr_src[min(row0 + 4, last)];
    int sr1 = csr_src[min(row0 + 5, last)];
    float c0[16], c1[16];
    {
      const float* e0 = ea_csr + (size_t)row0 * 16;
      const float* e1 = ea_csr + (size_t)min(row0 + 1, last) * 16;
#pragma unroll
      for (int k = 0; k < 16; ++k) { c0[k] = e0[k]; c1[k] = e1[k]; }
    }

    for (int p = row0; p < rend; p += 2) {
      // 1) issue gathers for p+4/p+5 with ALREADY-resident src ids (no wait)
      const float4 na0 = xl4[(size_t)sr0 * rs4 + coff];
      const float4 na1 = xl4[(size_t)sr1 * rs4 + coff];
      // 2) issue scalar loads: srcs for p+6/p+7, ea rows for p+2/p+3
      const int nsr0 = csr_src[min(p + 6, last)];
      const int nsr1 = csr_src[min(p + 7, last)];
      float cn0[16], cn1[16];
      {
        const float* e0 = ea_csr + (size_t)min(p + 2, last) * 16;
        const float* e1 = ea_csr + (size_t)min(p + 3, last) * 16;
#pragma unroll
        for (int k = 0; k < 16; ++k) { cn0[k] = e0[k]; cn1[k] = e1[k]; }
      }
      // 3) compute edges p, p+1 (covers the loads above)
      gat_edge_s<GS>(a0, c0, xrv, wef, attv, m, s, acc);
      if (p + 1 < rend) gat_edge_s<GS>(a1, c1, xrv, wef, attv, m, s, acc);
      // 4) rotate pipeline
      a0 = a2; a1 = a3; a2 = na0; a3 = na1;
      sr0 = nsr0; sr1 = nsr1;
#pragma unroll
      for (int k = 0; k < 16; ++k) { c0[k] = cn0[k]; c1[k] = cn1[k]; }
    }
  }

  const float inv = 1.f / (s + 1e-16f);
  float o[4];
  if (MODE == 0) {
    float bv[4];
    *reinterpret_cast<float4*>(bv) = *reinterpret_cast<const float4*>(&bias[col0]);
#pragma unroll
    for (int q = 0; q < 4; ++q) o[q] = fmaf(acc[q], inv, bv[q]);
    *reinterpret_cast<float4*>(&o_ptr[(size_t)dst * HCROW + col0]) =
        *reinterpret_cast<float4*>(o);
  } else {
#pragma unroll
    for (int q = 0; q < 4; ++q) {
      o[q] = acc[q] * inv;
      o[q] += __shfl_xor(o[q], 32);  // combine the slab's two heads
    }
    if (lane < 32)
      *reinterpret_cast<float4*>(&o_ptr[(size_t)dst * 128 + lane * 4]) =
          *reinterpret_cast<float4*>(o);
  }
}

// ---------- pooling: one block per graph, no atomics ----------
// h = 0.25*(hA+hB) + bias; out[g] = [max over nodes, mean over nodes]
__global__ __launch_bounds__(256) void pool_graph(
    const float* __restrict__ hA, const float* __restrict__ hB,
    const float* __restrict__ bias2, const int* __restrict__ gstart,
    const int* __restrict__ gend, float* __restrict__ out) {
  const int g = blockIdx.x;
  const int c = threadIdx.x & 127;
  const int sub = threadIdx.x >> 7;
  const int s0 = gstart[g], e0 = gend[g];
  const float b = bias2[c];
  float mx = -__builtin_inff(), sm = 0.f;
  for (int n = s0 + sub; n < e0; n += 2) {
    const float v = fmaf(0.25f, hA[(size_t)n * 128 + c] + hB[(size_t)n * 128 + c], b);
    mx = fmaxf(mx, v);
    sm += v;
  }
  __shared__ float smx[128], ssm[128];
  if (sub) { smx[c] = mx; ssm[c] = sm; }
  __syncthreads();
  if (!sub) {
    mx = fmaxf(mx, smx[c]);
    sm += ssm[c];
    const int cnt = e0 - s0;
    out[g * 256 + c] = (cnt > 0) ? mx : 0.f;
    out[g * 256 + 128 + c] = sm / fmaxf((float)cnt, 1.f);
  }
}

extern "C" void kernel_launch(void* const* d_in, const int* in_sizes, int n_in,
                              void* d_out, int out_size, void* d_ws, size_t ws_size,
                              hipStream_t stream) {
  const float* x     = (const float*)d_in[0];
  const float* ea    = (const float*)d_in[1];
  const int*   ei    = (const int*)d_in[2];
  const int*   batch = (const int*)d_in[3];
  const int N = in_sizes[0] / 128;  // 20000
  const int E = in_sizes[2] / 2;    // 640000
  const int NBINS = N * NB;
  const int bdiv = (N + NB - 1) / NB;  // 2500

  const float* Wl[3]   = {(const float*)d_in[4],  (const float*)d_in[11], (const float*)d_in[18]};
  const float* blv[3]  = {(const float*)d_in[5],  (const float*)d_in[12], (const float*)d_in[19]};
  const float* Wr[3]   = {(const float*)d_in[6],  (const float*)d_in[13], (const float*)d_in[20]};
  const float* brv[3]  = {(const float*)d_in[7],  (const float*)d_in[14], (const float*)d_in[21]};
  const float* Wev[3]  = {(const float*)d_in[8],  (const float*)d_in[15], (const float*)d_in[22]};
  const float* attv[3] = {(const float*)d_in[9],  (const float*)d_in[16], (const float*)d_in[23]};
  const float* bias[3] = {(const float*)d_in[10], (const float*)d_in[17], (const float*)d_in[24]};

  // ---- workspace layout (floats) ----
  float* ws = (float*)d_ws;
  float* xl     = ws;                          // N*512
  float* xr     = xl + (size_t)N * 512;        // N*512
  float* ea_csr = xr + (size_t)N * 512;        // E*16
  float* h      = ea_csr + (size_t)E * 16;     // N*256 (aliased: build ints / hsumA,B)
  int* kptr     = (int*)(h + (size_t)N * 256); // NBINS+1
  int* csr_src  = kptr + (NBINS + 1);          // E
  int* bsum     = csr_src + E;                 // <=257
  int* gstart   = bsum + 257;                  // 64
  int* gend     = gstart + 64;                 // 64
  // build-time temps aliased inside h (dead before h is first written):
  int* kcnt    = (int*)h;                      // NBINS
  int* kfill   = kcnt + NBINS;                 // NBINS
  // layer-2 head-pair partial sums aliased inside h (h dead after L2 GEMMs):
  float* hsumA = h;                            // N*128
  float* hsumB = h + (size_t)N * 128;          // N*128
  (void)n_in; (void)out_size; (void)ws_size;

  const int nodeBlocks = N / 16;
  const int edgeBlocks = (E + 255) / 256;
  const int scanBlocks = (NBINS + 1023) / 1024;  // 157
  const int gatBlocks = (N + 3) / 4;  // 4 waves/block, wave-per-dst

  // ---- bucketed CSR build + graph bounds ----
  hipMemsetAsync(kcnt, 0, (size_t)2 * NBINS * sizeof(int), stream);  // kcnt+kfill
  hipMemsetAsync(gstart, 0x7f, 64 * sizeof(int), stream);            // ~INT_MAX
  hipMemsetAsync(gend, 0, 64 * sizeof(int), stream);
  hist_b<<<edgeBlocks, 256, 0, stream>>>(ei, kcnt, batch, gstart, gend, E, N, bdiv);
  blk_scan<<<scanBlocks, 1024, 0, stream>>>(kcnt, kptr + 1, bsum, NBINS);
  scan_bsum<<<1, 256, 0, stream>>>(bsum, scanBlocks);
  add_off<<<(NBINS + 255) / 256, 256, 0, stream>>>(kptr, bsum, NBINS);
  csr_fill_b<<<edgeBlocks, 256, 0, stream>>>(ei, kptr, kfill, csr_src, ea, ea_csr, E, bdiv);

  // ================= layer 0 (K=128 -> hc=256, concat) =================
  node_gemm2<128, 256><<<2 * nodeBlocks, 256, 0, stream>>>(
      x, Wl[0], blv[0], xl, Wr[0], brv[0], xr, nodeBlocks);
  fused_gat<256, 0><<<gatBlocks, 256, 0, stream>>>(
      xl, xr, ea_csr, Wev[0], attv[0], bias[0], kptr, csr_src, h, nullptr, N);

  // ================= layer 1 (K=256 -> hc=256, concat) =================
  node_gemm2<256, 256><<<2 * nodeBlocks, 256, 0, stream>>>(
      h, Wl[1], blv[1], xl, Wr[1], brv[1], xr, nodeBlocks);
  fused_gat<256, 0><<<gatBlocks, 256, 0, stream>>>(
      xl, xr, ea_csr, Wev[1], attv[1], bias[1], kptr, csr_src, h, nullptr, N);

  // ================= layer 2 (K=256 -> hc=512, mean over heads) =================
  node_gemm2<256, 512><<<2 * nodeBlocks, 256, 0, stream>>>(
      h, Wl[2], blv[2], xl, Wr[2], brv[2], xr, nodeBlocks);
  fused_gat<512, 1><<<2 * gatBlocks, 256, 0, stream>>>(
      xl, xr, ea_csr, Wev[2], attv[2], bias[2], kptr, csr_src, hsumA, hsumB, N);

  // ================= pooling (mean-over-heads + bias fused, no atomics) ==========
  pool_graph<<<64, 256, 0, stream>>>(hsumA, hsumB, bias[2], gstart, gend, (float*)d_out);
}

// Round 13
// 1036.264 us; speedup vs baseline: 1.3996x; 1.0051x over previous
//
#include <hip/hip_runtime.h>

#define NB 8  // src buckets: edges of each dst are stored bucket-sorted

typedef float f32x2 __attribute__((ext_vector_type(2)));

// v_pk_fma_f32 with src0 broadcast from lo (HI=0) or hi (HI=1) half.
// d.x += x[HI]*w.x ; d.y += x[HI]*w.y  (2 FMAs in one instruction slot)
template <int HI>
__device__ __forceinline__ void pkfma_b(f32x2& d, const f32x2 x, const f32x2 w) {
  if constexpr (HI == 0)
    asm("v_pk_fma_f32 %0, %1, %2, %0 op_sel:[0,0,0] op_sel_hi:[0,1,1]"
        : "+v"(d) : "v"(x), "v"(w));
  else
    asm("v_pk_fma_f32 %0, %1, %2, %0 op_sel:[1,0,0] op_sel_hi:[1,1,1]"
        : "+v"(d) : "v"(x), "v"(w));
}

// ---------- node GEMM: computes BOTH Y1 = X@W1+b1 and Y2 = X@W2+b2 ----------
// grid = 2*nodeBlocks; first half -> (W1,b1,Y1), second half -> (W2,b2,Y2)
// Inner loop uses v_pk_fma_f32 (2 cols/inst); accumulation order per output
// element identical to the scalar version -> bit-identical results.
template <int K, int M>
__global__ __launch_bounds__(256) void node_gemm2(
    const float* __restrict__ X, const float* __restrict__ W1,
    const float* __restrict__ b1, float* __restrict__ Y1,
    const float* __restrict__ W2, const float* __restrict__ b2,
    float* __restrict__ Y2, int nodeBlocks) {
  constexpr int NPB = 16;
  constexpr int COLS4 = M / 4;
  constexpr int NG = 256 / COLS4;
  constexpr int RPN = NPB / NG;
  __shared__ float xs[NPB * K];
  const int tid = threadIdx.x;
  const int hi = blockIdx.x >= nodeBlocks;
  const float* W = hi ? W2 : W1;
  const float* bias = hi ? b2 : b1;
  float* Y = hi ? Y2 : Y1;
  const int n0 = (hi ? blockIdx.x - nodeBlocks : blockIdx.x) * NPB;
  {
    const float4* X4 = reinterpret_cast<const float4*>(X + (size_t)n0 * K);
    float4* xs4 = reinterpret_cast<float4*>(xs);
    for (int i = tid; i < NPB * K / 4; i += 256) xs4[i] = X4[i];
  }
  __syncthreads();
  const int c4 = (tid % COLS4) * 4;
  const int r0 = (tid / COLS4) * RPN;
  f32x2 acc[RPN][2];
#pragma unroll
  for (int r = 0; r < RPN; ++r)
#pragma unroll
    for (int q = 0; q < 2; ++q) acc[r][q] = (f32x2)(0.f);

  for (int k = 0; k < K; k += 4) {
    f32x2 xp[RPN][2];
#pragma unroll
    for (int r = 0; r < RPN; ++r) {
      const float4 t = *reinterpret_cast<const float4*>(&xs[(r0 + r) * K + k]);
      xp[r][0].x = t.x; xp[r][0].y = t.y;
      xp[r][1].x = t.z; xp[r][1].y = t.w;
    }
#pragma unroll
    for (int j2 = 0; j2 < 2; ++j2) {
      // W rows k+2*j2 (lo) and k+2*j2+1 (hi), 4 cols each as 2 f32x2
      const float4 t0 =
          *reinterpret_cast<const float4*>(&W[(size_t)(k + 2 * j2) * M + c4]);
      const float4 t1 =
          *reinterpret_cast<const float4*>(&W[(size_t)(k + 2 * j2 + 1) * M + c4]);
      f32x2 w0a, w0b, w1a, w1b;
      w0a.x = t0.x; w0a.y = t0.y; w0b.x = t0.z; w0b.y = t0.w;
      w1a.x = t1.x; w1a.y = t1.y; w1b.x = t1.z; w1b.y = t1.w;
#pragma unroll
      for (int r = 0; r < RPN; ++r) {
        pkfma_b<0>(acc[r][0], xp[r][j2], w0a);
        pkfma_b<0>(acc[r][1], xp[r][j2], w0b);
        pkfma_b<1>(acc[r][0], xp[r][j2], w1a);
        pkfma_b<1>(acc[r][1], xp[r][j2], w1b);
      }
    }
  }
  float bv[4];
  *reinterpret_cast<float4*>(bv) = *reinterpret_cast<const float4*>(&bias[c4]);
#pragma unroll
  for (int r = 0; r < RPN; ++r) {
    float o[4];
    o[0] = acc[r][0].x + bv[0];
    o[1] = acc[r][0].y + bv[1];
    o[2] = acc[r][1].x + bv[2];
    o[3] = acc[r][1].y + bv[3];
    *reinterpret_cast<float4*>(&Y[(size_t)(n0 + r0 + r) * M + c4]) =
        *reinterpret_cast<float4*>(o);
  }
}

// ---------- bucketed CSR build: key = dst*NB + src/bdiv ----------
// also computes per-graph node bounds (batch is sorted)
__global__ void hist_b(const int* __restrict__ ei, int* __restrict__ kcnt,
                       const int* __restrict__ batch, int* __restrict__ gstart,
                       int* __restrict__ gend, int E, int N, int bdiv) {
  int i = blockIdx.x * blockDim.x + threadIdx.x;
  if (i < E) atomicAdd(&kcnt[ei[E + i] * NB + ei[i] / bdiv], 1);
  if (i < N) {
    int g = batch[i];
    atomicMin(&gstart[g], i);
    atomicMax(&gend[g], i + 1);
  }
}

__global__ __launch_bounds__(1024) void blk_scan(
    const int* __restrict__ in, int* __restrict__ out1, int* __restrict__ bsum, int n) {
  __shared__ int buf[1024];
  const int tid = threadIdx.x;
  const int gid = blockIdx.x * 1024 + tid;
  int v = (gid < n) ? in[gid] : 0;
  buf[tid] = v;
  __syncthreads();
  for (int off = 1; off < 1024; off <<= 1) {
    int t = (tid >= off) ? buf[tid - off] : 0;
    __syncthreads();
    buf[tid] += t;
    __syncthreads();
  }
  if (gid < n) out1[gid] = buf[tid];
  if (tid == 1023) bsum[blockIdx.x] = buf[1023];
}

// one-block LDS inclusive scan of the per-block sums (nb <= 256)
__global__ __launch_bounds__(256) void scan_bsum(int* __restrict__ bsum, int nb) {
  __shared__ int buf[256];
  const int tid = threadIdx.x;
  int v = (tid < nb) ? bsum[tid] : 0;
  buf[tid] = v;
  __syncthreads();
  for (int off = 1; off < 256; off <<= 1) {
    int t = (tid >= off) ? buf[tid - off] : 0;
    __syncthreads();
    buf[tid] += t;
    __syncthreads();
  }
  if (tid < nb) bsum[tid] = buf[tid];
}

__global__ void add_off(int* __restrict__ kptr, const int* __restrict__ bsum, int n) {
  int gid = blockIdx.x * blockDim.x + threadIdx.x;
  if (gid == 0) kptr[0] = 0;
  if (gid < n) {
    int blk = gid >> 10;
    if (blk > 0) kptr[1 + gid] += bsum[blk - 1];
  }
}

// fill CSR src ids AND scatter edge_attr rows into CSR order in the same pass
// (ea read is streaming/coalesced: thread i reads ea[i*16..i*16+15])
__global__ void csr_fill_b(const int* __restrict__ ei, const int* __restrict__ kptr,
                           int* __restrict__ kfill, int* __restrict__ csr_src,
                           const float* __restrict__ ea, float* __restrict__ ea_csr,
                           int E, int bdiv) {
  int i = blockIdx.x * blockDim.x + threadIdx.x;
  if (i < E) {
    int src = ei[i], dst = ei[E + i];
    int key = dst * NB + src / bdiv;
    int slot = kptr[key] + atomicAdd(&kfill[key], 1);
    csr_src[slot] = src;
    const float4* es = reinterpret_cast<const float4*>(ea) + (size_t)i * 4;
    float4* ed = reinterpret_cast<float4*>(ea_csr) + (size_t)slot * 4;
    float4 v0 = es[0], v1 = es[1], v2 = es[2], v3 = es[3];
    ed[0] = v0; ed[1] = v1; ed[2] = v2; ed[3] = v3;
  }
}

// ---------- one edge of fused GATv2 with SGPR-resident ea coefficients ----------
template <int GS>
__device__ __forceinline__ void gat_edge_s(
    const float4 a, const float (&c)[16], const float4 xv,
    const float (&wef)[16][4], const float (&attv)[4],
    float& m, float& s, float (&acc)[4]) {
  float mv[4] = {a.x + xv.x, a.y + xv.y, a.z + xv.z, a.w + xv.w};
#pragma unroll
  for (int k = 0; k < 16; ++k) {
#pragma unroll
    for (int q = 0; q < 4; ++q) mv[q] = fmaf(c[k], wef[k][q], mv[q]);
  }
  float l = 0.f;
#pragma unroll
  for (int q = 0; q < 4; ++q) {
    const float v = fmaxf(mv[q], 0.2f * mv[q]);  // leaky-relu
    l = fmaf(v, attv[q], l);
  }
#pragma unroll
  for (int off = 1; off < GS; off <<= 1) l += __shfl_xor(l, off);
  const float nm = fmaxf(m, l);
  const float sc = __expf(m - nm);
  const float pe = __expf(l - nm);
  m = nm;
  s = fmaf(s, sc, pe);
  acc[0] = fmaf(pe, a.x, acc[0] * sc);
  acc[1] = fmaf(pe, a.y, acc[1] * sc);
  acc[2] = fmaf(pe, a.z, acc[2] * sc);
  acc[3] = fmaf(pe, a.w, acc[3] * sc);
}

// ---------- fused per-dst GATv2: wave-per-dst, scalar edge metadata ----------
// One wave owns one dst (256-column slab). Edge index p, src id, and the
// 16-float ea row are wave-uniform -> scalar loads (s_load), SGPR operands in
// the FMA chain. Gather pipeline: 4 xl rows in flight.
// MODE 0: concat -> out[dst*HCROW + col0] = acc/s + bias  (grid = gb)
// MODE 1: layer-2 head-pair partial mean; grid = 2*gb: first half writes out
//         (cols 0..255, heads 0/1), second half outB (cols 256..511, heads 2/3)
template <int HCROW, int MODE>
__global__ __launch_bounds__(256) void fused_gat(
    const float* __restrict__ xl, const float* __restrict__ xr,
    const float* __restrict__ ea_csr, const float* __restrict__ We,
    const float* __restrict__ att, const float* __restrict__ bias,
    const int* __restrict__ kptr, const int* __restrict__ csr_src,
    float* __restrict__ out, float* __restrict__ outB, int N) {
  constexpr int C = HCROW / 4;   // per-head dim (64 or 128)
  constexpr int GS = C / 4;      // lanes per head group (16 or 32)
  const int lane = threadIdx.x & 63;
  const int wslot = threadIdx.x >> 6;
  int bx = blockIdx.x;
  int colbase = 0;
  float* o_ptr = out;
  if (MODE == 1) {
    const int gb = gridDim.x >> 1;
    if (bx >= gb) { bx -= gb; colbase = 256; o_ptr = outB; }
  }
  const int dst = bx * 4 + wslot;
  if (dst >= N) return;

  float wef[16][4];
#pragma unroll
  for (int k = 0; k < 16; ++k)
    *reinterpret_cast<float4*>(wef[k]) =
        *reinterpret_cast<const float4*>(&We[k * HCROW + colbase + lane * 4]);
  const int col0 = colbase + lane * 4;
  const int head = col0 / C;
  float attv[4];
  *reinterpret_cast<float4*>(attv) =
      *reinterpret_cast<const float4*>(&att[head * C + (col0 % C)]);
  const float4* xl4 = reinterpret_cast<const float4*>(xl);
  const int rs4 = HCROW / 4;
  const int coff = col0 >> 2;
  const float4 xrv =
      reinterpret_cast<const float4*>(xr)[(size_t)dst * rs4 + coff];

  // wave-uniform row range (readfirstlane anchors uniformity -> s_load chain)
  const int row0 = __builtin_amdgcn_readfirstlane(kptr[dst * NB]);
  const int rend = __builtin_amdgcn_readfirstlane(kptr[dst * NB + NB]);

  float m = -__builtin_inff(), s = 0.f;
  float acc[4] = {0.f, 0.f, 0.f, 0.f};

  if (row0 < rend) {
    const int last = rend - 1;
    // prologue: 4 gather rows in flight, current ea pair, src pair for p+4/5
    const int s0 = csr_src[row0];
    const int s1 = csr_src[min(row0 + 1, last)];
    const int s2 = csr_src[min(row0 + 2, last)];
    const int s3 = csr_src[min(row0 + 3, last)];
    float4 a0 = xl4[(size_t)s0 * rs4 + coff];
    float4 a1 = xl4[(size_t)s1 * rs4 + coff];
    float4 a2 = xl4[(size_t)s2 * rs4 + coff];
    float4 a3 = xl4[(size_t)s3 * rs4 + coff];
    int sr0 = csr_src[min(row0 + 4, last)];
    int sr1 = csr_src[min(row0 + 5, last)];
    float c0[16], c1[16];
    {
      const float* e0 = ea_csr + (size_t)row0 * 16;
      const float* e1 = ea_csr + (size_t)min(row0 + 1, last) * 16;
#pragma unroll
      for (int k = 0; k < 16; ++k) { c0[k] = e0[k]; c1[k] = e1[k]; }
    }

    for (int p = row0; p < rend; p += 2) {
      // 1) issue gathers for p+4/p+5 with ALREADY-resident src ids (no wait)
      const float4 na0 = xl4[(size_t)sr0 * rs4 + coff];
      const float4 na1 = xl4[(size_t)sr1 * rs4 + coff];
      // 2) issue scalar loads: srcs for p+6/p+7, ea rows for p+2/p+3
      const int nsr0 = csr_src[min(p + 6, last)];
      const int nsr1 = csr_src[min(p + 7, last)];
      float cn0[16], cn1[16];
      {
        const float* e0 = ea_csr + (size_t)min(p + 2, last) * 16;
        const float* e1 = ea_csr + (size_t)min(p + 3, last) * 16;
#pragma unroll
        for (int k = 0; k < 16; ++k) { cn0[k] = e0[k]; cn1[k] = e1[k]; }
      }
      // 3) compute edges p, p+1 (covers the loads above)
      gat_edge_s<GS>(a0, c0, xrv, wef, attv, m, s, acc);
      if (p + 1 < rend) gat_edge_s<GS>(a1, c1, xrv, wef, attv, m, s, acc);
      // 4) rotate pipeline
      a0 = a2; a1 = a3; a2 = na0; a3 = na1;
      sr0 = nsr0; sr1 = nsr1;
#pragma unroll
      for (int k = 0; k < 16; ++k) { c0[k] = cn0[k]; c1[k] = cn1[k]; }
    }
  }

  const float inv = 1.f / (s + 1e-16f);
  float o[4];
  if (MODE == 0) {
    float bv[4];
    *reinterpret_cast<float4*>(bv) = *reinterpret_cast<const float4*>(&bias[col0]);
#pragma unroll
    for (int q = 0; q < 4; ++q) o[q] = fmaf(acc[q], inv, bv[q]);
    *reinterpret_cast<float4*>(&o_ptr[(size_t)dst * HCROW + col0]) =
        *reinterpret_cast<float4*>(o);
  } else {
#pragma unroll
    for (int q = 0; q < 4; ++q) {
      o[q] = acc[q] * inv;
      o[q] += __shfl_xor(o[q], 32);  // combine the slab's two heads
    }
    if (lane < 32)
      *reinterpret_cast<float4*>(&o_ptr[(size_t)dst * 128 + lane * 4]) =
          *reinterpret_cast<float4*>(o);
  }
}

// ---------- pooling: one block per graph, no atomics ----------
// h = 0.25*(hA+hB) + bias; out[g] = [max over nodes, mean over nodes]
__global__ __launch_bounds__(256) void pool_graph(
    const float* __restrict__ hA, const float* __restrict__ hB,
    const float* __restrict__ bias2, const int* __restrict__ gstart,
    const int* __restrict__ gend, float* __restrict__ out) {
  const int g = blockIdx.x;
  const int c = threadIdx.x & 127;
  const int sub = threadIdx.x >> 7;
  const int s0 = gstart[g], e0 = gend[g];
  const float b = bias2[c];
  float mx = -__builtin_inff(), sm = 0.f;
  for (int n = s0 + sub; n < e0; n += 2) {
    const float v = fmaf(0.25f, hA[(size_t)n * 128 + c] + hB[(size_t)n * 128 + c], b);
    mx = fmaxf(mx, v);
    sm += v;
  }
  __shared__ float smx[128], ssm[128];
  if (sub) { smx[c] = mx; ssm[c] = sm; }
  __syncthreads();
  if (!sub) {
    mx = fmaxf(mx, smx[c]);
    sm += ssm[c];
    const int cnt = e0 - s0;
    out[g * 256 + c] = (cnt > 0) ? mx : 0.f;
    out[g * 256 + 128 + c] = sm / fmaxf((float)cnt, 1.f);
  }
}

extern "C" void kernel_launch(void* const* d_in, const int* in_sizes, int n_in,
                              void* d_out, int out_size, void* d_ws, size_t ws_size,
                              hipStream_t stream) {
  const float* x     = (const float*)d_in[0];
  const float* ea    = (const float*)d_in[1];
  const int*   ei    = (const int*)d_in[2];
  const int*   batch = (const int*)d_in[3];
  const int N = in_sizes[0] / 128;  // 20000
  const int E = in_sizes[2] / 2;    // 640000
  const int NBINS = N * NB;
  const int bdiv = (N + NB - 1) / NB;  // 2500

  const float* Wl[3]   = {(const float*)d_in[4],  (const float*)d_in[11], (const float*)d_in[18]};
  const float* blv[3]  = {(const float*)d_in[5],  (const float*)d_in[12], (const float*)d_in[19]};
  const float* Wr[3]   = {(const float*)d_in[6],  (const float*)d_in[13], (const float*)d_in[20]};
  const float* brv[3]  = {(const float*)d_in[7],  (const float*)d_in[14], (const float*)d_in[21]};
  const float* Wev[3]  = {(const float*)d_in[8],  (const float*)d_in[15], (const float*)d_in[22]};
  const float* attv[3] = {(const float*)d_in[9],  (const float*)d_in[16], (const float*)d_in[23]};
  const float* bias[3] = {(const float*)d_in[10], (const float*)d_in[17], (const float*)d_in[24]};

  // ---- workspace layout (floats) ----
  float* ws = (float*)d_ws;
  float* xl     = ws;                          // N*512
  float* xr     = xl + (size_t)N * 512;        // N*512
  float* ea_csr = xr + (size_t)N * 512;        // E*16
  float* h      = ea_csr + (size_t)E * 16;     // N*256 (aliased: build ints / hsumA,B)
  int* kptr     = (int*)(h + (size_t)N * 256); // NBINS+1
  int* csr_src  = kptr + (NBINS + 1);          // E
  int* bsum     = csr_src + E;                 // <=257
  int* gstart   = bsum + 257;                  // 64
  int* gend     = gstart + 64;                 // 64
  // build-time temps aliased inside h (dead before h is first written):
  int* kcnt    = (int*)h;                      // NBINS
  int* kfill   = kcnt + NBINS;                 // NBINS
  // layer-2 head-pair partial sums aliased inside h (h dead after L2 GEMMs):
  float* hsumA = h;                            // N*128
  float* hsumB = h + (size_t)N * 128;          // N*128
  (void)n_in; (void)out_size; (void)ws_size;

  const int nodeBlocks = N / 16;
  const int edgeBlocks = (E + 255) / 256;
  const int scanBlocks = (NBINS + 1023) / 1024;  // 157
  const int gatBlocks = (N + 3) / 4;  // 4 waves/block, wave-per-dst

  // ---- bucketed CSR build + graph bounds ----
  hipMemsetAsync(kcnt, 0, (size_t)2 * NBINS * sizeof(int), stream);  // kcnt+kfill
  hipMemsetAsync(gstart, 0x7f, 64 * sizeof(int), stream);            // ~INT_MAX
  hipMemsetAsync(gend, 0, 64 * sizeof(int), stream);
  hist_b<<<edgeBlocks, 256, 0, stream>>>(ei, kcnt, batch, gstart, gend, E, N, bdiv);
  blk_scan<<<scanBlocks, 1024, 0, stream>>>(kcnt, kptr + 1, bsum, NBINS);
  scan_bsum<<<1, 256, 0, stream>>>(bsum, scanBlocks);
  add_off<<<(NBINS + 255) / 256, 256, 0, stream>>>(kptr, bsum, NBINS);
  csr_fill_b<<<edgeBlocks, 256, 0, stream>>>(ei, kptr, kfill, csr_src, ea, ea_csr, E, bdiv);

  // ================= layer 0 (K=128 -> hc=256, concat) =================
  node_gemm2<128, 256><<<2 * nodeBlocks, 256, 0, stream>>>(
      x, Wl[0], blv[0], xl, Wr[0], brv[0], xr, nodeBlocks);
  fused_gat<256, 0><<<gatBlocks, 256, 0, stream>>>(
      xl, xr, ea_csr, Wev[0], attv[0], bias[0], kptr, csr_src, h, nullptr, N);

  // ================= layer 1 (K=256 -> hc=256, concat) =================
  node_gemm2<256, 256><<<2 * nodeBlocks, 256, 0, stream>>>(
      h, Wl[1], blv[1], xl, Wr[1], brv[1], xr, nodeBlocks);
  fused_gat<256, 0><<<gatBlocks, 256, 0, stream>>>(
      xl, xr, ea_csr, Wev[1], attv[1], bias[1], kptr, csr_src, h, nullptr, N);

  // ================= layer 2 (K=256 -> hc=512, mean over heads) =================
  node_gemm2<256, 512><<<2 * nodeBlocks, 256, 0, stream>>>(
      h, Wl[2], blv[2], xl, Wr[2], brv[2], xr, nodeBlocks);
  fused_gat<512, 1><<<2 * gatBlocks, 256, 0, stream>>>(
      xl, xr, ea_csr, Wev[2], attv[2], bias[2], kptr, csr_src, hsumA, hsumB, N);

  // ================= pooling (mean-over-heads + bias fused, no atomics) ==========
  pool_graph<<<64, 256, 0, stream>>>(hsumA, hsumB, bias[2], gstart, gend, (float*)d_out);
}

// Round 14
// 1006.614 us; speedup vs baseline: 1.4408x; 1.0295x over previous
//
#include <hip/hip_runtime.h>

#define NB 8  // src buckets: edges of each dst are stored bucket-sorted

typedef float f32x2 __attribute__((ext_vector_type(2)));

// v_pk_fma_f32 with src0 broadcast from lo (HI=0) or hi (HI=1) half.
// d.x += x[HI]*w.x ; d.y += x[HI]*w.y  (2 FMAs in one instruction slot)
template <int HI>
__device__ __forceinline__ void pkfma_b(f32x2& d, const f32x2 x, const f32x2 w) {
  if constexpr (HI == 0)
    asm("v_pk_fma_f32 %0, %1, %2, %0 op_sel:[0,0,0] op_sel_hi:[0,1,1]"
        : "+v"(d) : "v"(x), "v"(w));
  else
    asm("v_pk_fma_f32 %0, %1, %2, %0 op_sel:[1,0,0] op_sel_hi:[1,1,1]"
        : "+v"(d) : "v"(x), "v"(w));
}

// ---------- node GEMM: computes BOTH Y1 = X@W1+b1 and Y2 = X@W2+b2 ----------
// grid = 2*nodeBlocks; first half -> (W1,b1,Y1), second half -> (W2,b2,Y2)
// NPB nodes per block; RPN = NPB / (256/(M/4)) rows per thread. Each W load
// feeds RPN FMAs -> bigger NPB = higher arithmetic intensity.
template <int K, int M, int NPB>
__global__ __launch_bounds__(256) void node_gemm2(
    const float* __restrict__ X, const float* __restrict__ W1,
    const float* __restrict__ b1, float* __restrict__ Y1,
    const float* __restrict__ W2, const float* __restrict__ b2,
    float* __restrict__ Y2, int nodeBlocks) {
  constexpr int COLS4 = M / 4;
  constexpr int NG = 256 / COLS4;
  constexpr int RPN = NPB / NG;
  __shared__ float xs[NPB * K];
  const int tid = threadIdx.x;
  const int hi = blockIdx.x >= nodeBlocks;
  const float* W = hi ? W2 : W1;
  const float* bias = hi ? b2 : b1;
  float* Y = hi ? Y2 : Y1;
  const int n0 = (hi ? blockIdx.x - nodeBlocks : blockIdx.x) * NPB;
  {
    const float4* X4 = reinterpret_cast<const float4*>(X + (size_t)n0 * K);
    float4* xs4 = reinterpret_cast<float4*>(xs);
    for (int i = tid; i < NPB * K / 4; i += 256) xs4[i] = X4[i];
  }
  __syncthreads();
  const int c4 = (tid % COLS4) * 4;
  const int r0 = (tid / COLS4) * RPN;
  f32x2 acc[RPN][2];
#pragma unroll
  for (int r = 0; r < RPN; ++r)
#pragma unroll
    for (int q = 0; q < 2; ++q) acc[r][q] = (f32x2)(0.f);

  for (int k = 0; k < K; k += 4) {
    f32x2 xp[RPN][2];
#pragma unroll
    for (int r = 0; r < RPN; ++r) {
      const float4 t = *reinterpret_cast<const float4*>(&xs[(r0 + r) * K + k]);
      xp[r][0].x = t.x; xp[r][0].y = t.y;
      xp[r][1].x = t.z; xp[r][1].y = t.w;
    }
#pragma unroll
    for (int j2 = 0; j2 < 2; ++j2) {
      // W rows k+2*j2 (lo) and k+2*j2+1 (hi), 4 cols each as 2 f32x2
      const float4 t0 =
          *reinterpret_cast<const float4*>(&W[(size_t)(k + 2 * j2) * M + c4]);
      const float4 t1 =
          *reinterpret_cast<const float4*>(&W[(size_t)(k + 2 * j2 + 1) * M + c4]);
      f32x2 w0a, w0b, w1a, w1b;
      w0a.x = t0.x; w0a.y = t0.y; w0b.x = t0.z; w0b.y = t0.w;
      w1a.x = t1.x; w1a.y = t1.y; w1b.x = t1.z; w1b.y = t1.w;
#pragma unroll
      for (int r = 0; r < RPN; ++r) {
        pkfma_b<0>(acc[r][0], xp[r][j2], w0a);
        pkfma_b<0>(acc[r][1], xp[r][j2], w0b);
        pkfma_b<1>(acc[r][0], xp[r][j2], w1a);
        pkfma_b<1>(acc[r][1], xp[r][j2], w1b);
      }
    }
  }
  float bv[4];
  *reinterpret_cast<float4*>(bv) = *reinterpret_cast<const float4*>(&bias[c4]);
#pragma unroll
  for (int r = 0; r < RPN; ++r) {
    float o[4];
    o[0] = acc[r][0].x + bv[0];
    o[1] = acc[r][0].y + bv[1];
    o[2] = acc[r][1].x + bv[2];
    o[3] = acc[r][1].y + bv[3];
    *reinterpret_cast<float4*>(&Y[(size_t)(n0 + r0 + r) * M + c4]) =
        *reinterpret_cast<float4*>(o);
  }
}

// ---------- bucketed CSR build: key = dst*NB + src/bdiv ----------
// also computes per-graph node bounds (batch is sorted)
__global__ void hist_b(const int* __restrict__ ei, int* __restrict__ kcnt,
                       const int* __restrict__ batch, int* __restrict__ gstart,
                       int* __restrict__ gend, int E, int N, int bdiv) {
  int i = blockIdx.x * blockDim.x + threadIdx.x;
  if (i < E) atomicAdd(&kcnt[ei[E + i] * NB + ei[i] / bdiv], 1);
  if (i < N) {
    int g = batch[i];
    atomicMin(&gstart[g], i);
    atomicMax(&gend[g], i + 1);
  }
}

__global__ __launch_bounds__(1024) void blk_scan(
    const int* __restrict__ in, int* __restrict__ out1, int* __restrict__ bsum, int n) {
  __shared__ int buf[1024];
  const int tid = threadIdx.x;
  const int gid = blockIdx.x * 1024 + tid;
  int v = (gid < n) ? in[gid] : 0;
  buf[tid] = v;
  __syncthreads();
  for (int off = 1; off < 1024; off <<= 1) {
    int t = (tid >= off) ? buf[tid - off] : 0;
    __syncthreads();
    buf[tid] += t;
    __syncthreads();
  }
  if (gid < n) out1[gid] = buf[tid];
  if (tid == 1023) bsum[blockIdx.x] = buf[1023];
}

// one-block LDS inclusive scan of the per-block sums (nb <= 256)
__global__ __launch_bounds__(256) void scan_bsum(int* __restrict__ bsum, int nb) {
  __shared__ int buf[256];
  const int tid = threadIdx.x;
  int v = (tid < nb) ? bsum[tid] : 0;
  buf[tid] = v;
  __syncthreads();
  for (int off = 1; off < 256; off <<= 1) {
    int t = (tid >= off) ? buf[tid - off] : 0;
    __syncthreads();
    buf[tid] += t;
    __syncthreads();
  }
  if (tid < nb) bsum[tid] = buf[tid];
}

__global__ void add_off(int* __restrict__ kptr, const int* __restrict__ bsum, int n) {
  int gid = blockIdx.x * blockDim.x + threadIdx.x;
  if (gid == 0) kptr[0] = 0;
  if (gid < n) {
    int blk = gid >> 10;
    if (blk > 0) kptr[1 + gid] += bsum[blk - 1];
  }
}

// fill CSR src ids AND scatter edge_attr rows into CSR order in the same pass
// (ea read is streaming/coalesced: thread i reads ea[i*16..i*16+15])
__global__ void csr_fill_b(const int* __restrict__ ei, const int* __restrict__ kptr,
                           int* __restrict__ kfill, int* __restrict__ csr_src,
                           const float* __restrict__ ea, float* __restrict__ ea_csr,
                           int E, int bdiv) {
  int i = blockIdx.x * blockDim.x + threadIdx.x;
  if (i < E) {
    int src = ei[i], dst = ei[E + i];
    int key = dst * NB + src / bdiv;
    int slot = kptr[key] + atomicAdd(&kfill[key], 1);
    csr_src[slot] = src;
    const float4* es = reinterpret_cast<const float4*>(ea) + (size_t)i * 4;
    float4* ed = reinterpret_cast<float4*>(ea_csr) + (size_t)slot * 4;
    float4 v0 = es[0], v1 = es[1], v2 = es[2], v3 = es[3];
    ed[0] = v0; ed[1] = v1; ed[2] = v2; ed[3] = v3;
  }
}

// ---------- one edge of fused GATv2 with SGPR-resident ea coefficients ----------
template <int GS>
__device__ __forceinline__ void gat_edge_s(
    const float4 a, const float (&c)[16], const float4 xv,
    const float (&wef)[16][4], const float (&attv)[4],
    float& m, float& s, float (&acc)[4]) {
  float mv[4] = {a.x + xv.x, a.y + xv.y, a.z + xv.z, a.w + xv.w};
#pragma unroll
  for (int k = 0; k < 16; ++k) {
#pragma unroll
    for (int q = 0; q < 4; ++q) mv[q] = fmaf(c[k], wef[k][q], mv[q]);
  }
  float l = 0.f;
#pragma unroll
  for (int q = 0; q < 4; ++q) {
    const float v = fmaxf(mv[q], 0.2f * mv[q]);  // leaky-relu
    l = fmaf(v, attv[q], l);
  }
#pragma unroll
  for (int off = 1; off < GS; off <<= 1) l += __shfl_xor(l, off);
  const float nm = fmaxf(m, l);
  const float sc = __expf(m - nm);
  const float pe = __expf(l - nm);
  m = nm;
  s = fmaf(s, sc, pe);
  acc[0] = fmaf(pe, a.x, acc[0] * sc);
  acc[1] = fmaf(pe, a.y, acc[1] * sc);
  acc[2] = fmaf(pe, a.z, acc[2] * sc);
  acc[3] = fmaf(pe, a.w, acc[3] * sc);
}

// ---------- fused per-dst GATv2: wave-per-dst, scalar edge metadata ----------
// One wave owns one dst (256-column slab). Edge index p, src id, and the
// 16-float ea row are wave-uniform -> scalar loads (s_load), SGPR operands in
// the FMA chain. Gather pipeline: 4 xl rows in flight.
// MODE 0: concat -> out[dst*HCROW + col0] = acc/s + bias  (grid = gb)
// MODE 1: layer-2 head-pair partial mean; grid = 2*gb: first half writes out
//         (cols 0..255, heads 0/1), second half outB (cols 256..511, heads 2/3)
template <int HCROW, int MODE>
__global__ __launch_bounds__(256) void fused_gat(
    const float* __restrict__ xl, const float* __restrict__ xr,
    const float* __restrict__ ea_csr, const float* __restrict__ We,
    const float* __restrict__ att, const float* __restrict__ bias,
    const int* __restrict__ kptr, const int* __restrict__ csr_src,
    float* __restrict__ out, float* __restrict__ outB, int N) {
  constexpr int C = HCROW / 4;   // per-head dim (64 or 128)
  constexpr int GS = C / 4;      // lanes per head group (16 or 32)
  const int lane = threadIdx.x & 63;
  const int wslot = threadIdx.x >> 6;
  int bx = blockIdx.x;
  int colbase = 0;
  float* o_ptr = out;
  if (MODE == 1) {
    const int gb = gridDim.x >> 1;
    if (bx >= gb) { bx -= gb; colbase = 256; o_ptr = outB; }
  }
  const int dst = bx * 4 + wslot;
  if (dst >= N) return;

  float wef[16][4];
#pragma unroll
  for (int k = 0; k < 16; ++k)
    *reinterpret_cast<float4*>(wef[k]) =
        *reinterpret_cast<const float4*>(&We[k * HCROW + colbase + lane * 4]);
  const int col0 = colbase + lane * 4;
  const int head = col0 / C;
  float attv[4];
  *reinterpret_cast<float4*>(attv) =
      *reinterpret_cast<const float4*>(&att[head * C + (col0 % C)]);
  const float4* xl4 = reinterpret_cast<const float4*>(xl);
  const int rs4 = HCROW / 4;
  const int coff = col0 >> 2;
  const float4 xrv =
      reinterpret_cast<const float4*>(xr)[(size_t)dst * rs4 + coff];

  // wave-uniform row range (readfirstlane anchors uniformity -> s_load chain)
  const int row0 = __builtin_amdgcn_readfirstlane(kptr[dst * NB]);
  const int rend = __builtin_amdgcn_readfirstlane(kptr[dst * NB + NB]);

  float m = -__builtin_inff(), s = 0.f;
  float acc[4] = {0.f, 0.f, 0.f, 0.f};

  if (row0 < rend) {
    const int last = rend - 1;
    // prologue: 4 gather rows in flight, current ea pair, src pair for p+4/5
    const int s0 = csr_src[row0];
    const int s1 = csr_src[min(row0 + 1, last)];
    const int s2 = csr_src[min(row0 + 2, last)];
    const int s3 = csr_src[min(row0 + 3, last)];
    float4 a0 = xl4[(size_t)s0 * rs4 + coff];
    float4 a1 = xl4[(size_t)s1 * rs4 + coff];
    float4 a2 = xl4[(size_t)s2 * rs4 + coff];
    float4 a3 = xl4[(size_t)s3 * rs4 + coff];
    int sr0 = csr_src[min(row0 + 4, last)];
    int sr1 = csr_src[min(row0 + 5, last)];
    float c0[16], c1[16];
    {
      const float* e0 = ea_csr + (size_t)row0 * 16;
      const float* e1 = ea_csr + (size_t)min(row0 + 1, last) * 16;
#pragma unroll
      for (int k = 0; k < 16; ++k) { c0[k] = e0[k]; c1[k] = e1[k]; }
    }

    for (int p = row0; p < rend; p += 2) {
      // 1) issue gathers for p+4/p+5 with ALREADY-resident src ids (no wait)
      const float4 na0 = xl4[(size_t)sr0 * rs4 + coff];
      const float4 na1 = xl4[(size_t)sr1 * rs4 + coff];
      // 2) issue scalar loads: srcs for p+6/p+7, ea rows for p+2/p+3
      const int nsr0 = csr_src[min(p + 6, last)];
      const int nsr1 = csr_src[min(p + 7, last)];
      float cn0[16], cn1[16];
      {
        const float* e0 = ea_csr + (size_t)min(p + 2, last) * 16;
        const float* e1 = ea_csr + (size_t)min(p + 3, last) * 16;
#pragma unroll
        for (int k = 0; k < 16; ++k) { cn0[k] = e0[k]; cn1[k] = e1[k]; }
      }
      // 3) compute edges p, p+1 (covers the loads above)
      gat_edge_s<GS>(a0, c0, xrv, wef, attv, m, s, acc);
      if (p + 1 < rend) gat_edge_s<GS>(a1, c1, xrv, wef, attv, m, s, acc);
      // 4) rotate pipeline
      a0 = a2; a1 = a3; a2 = na0; a3 = na1;
      sr0 = nsr0; sr1 = nsr1;
#pragma unroll
      for (int k = 0; k < 16; ++k) { c0[k] = cn0[k]; c1[k] = cn1[k]; }
    }
  }

  const float inv = 1.f / (s + 1e-16f);
  float o[4];
  if (MODE == 0) {
    float bv[4];
    *reinterpret_cast<float4*>(bv) = *reinterpret_cast<const float4*>(&bias[col0]);
#pragma unroll
    for (int q = 0; q < 4; ++q) o[q] = fmaf(acc[q], inv, bv[q]);
    *reinterpret_cast<float4*>(&o_ptr[(size_t)dst * HCROW + col0]) =
        *reinterpret_cast<float4*>(o);
  } else {
#pragma unroll
    for (int q = 0; q < 4; ++q) {
      o[q] = acc[q] * inv;
      o[q] += __shfl_xor(o[q], 32);  // combine the slab's two heads
    }
    if (lane < 32)
      *reinterpret_cast<float4*>(&o_ptr[(size_t)dst * 128 + lane * 4]) =
          *reinterpret_cast<float4*>(o);
  }
}

// ---------- pooling: one block per graph, no atomics ----------
// h = 0.25*(hA+hB) + bias; out[g] = [max over nodes, mean over nodes]
__global__ __launch_bounds__(256) void pool_graph(
    const float* __restrict__ hA, const float* __restrict__ hB,
    const float* __restrict__ bias2, const int* __restrict__ gstart,
    const int* __restrict__ gend, float* __restrict__ out) {
  const int g = blockIdx.x;
  const int c = threadIdx.x & 127;
  const int sub = threadIdx.x >> 7;
  const int s0 = gstart[g], e0 = gend[g];
  const float b = bias2[c];
  float mx = -__builtin_inff(), sm = 0.f;
  for (int n = s0 + sub; n < e0; n += 2) {
    const float v = fmaf(0.25f, hA[(size_t)n * 128 + c] + hB[(size_t)n * 128 + c], b);
    mx = fmaxf(mx, v);
    sm += v;
  }
  __shared__ float smx[128], ssm[128];
  if (sub) { smx[c] = mx; ssm[c] = sm; }
  __syncthreads();
  if (!sub) {
    mx = fmaxf(mx, smx[c]);
    sm += ssm[c];
    const int cnt = e0 - s0;
    out[g * 256 + c] = (cnt > 0) ? mx : 0.f;
    out[g * 256 + 128 + c] = sm / fmaxf((float)cnt, 1.f);
  }
}

extern "C" void kernel_launch(void* const* d_in, const int* in_sizes, int n_in,
                              void* d_out, int out_size, void* d_ws, size_t ws_size,
                              hipStream_t stream) {
  const float* x     = (const float*)d_in[0];
  const float* ea    = (const float*)d_in[1];
  const int*   ei    = (const int*)d_in[2];
  const int*   batch = (const int*)d_in[3];
  const int N = in_sizes[0] / 128;  // 20000
  const int E = in_sizes[2] / 2;    // 640000
  const int NBINS = N * NB;
  const int bdiv = (N + NB - 1) / NB;  // 2500

  const float* Wl[3]   = {(const float*)d_in[4],  (const float*)d_in[11], (const float*)d_in[18]};
  const float* blv[3]  = {(const float*)d_in[5],  (const float*)d_in[12], (const float*)d_in[19]};
  const float* Wr[3]   = {(const float*)d_in[6],  (const float*)d_in[13], (const float*)d_in[20]};
  const float* brv[3]  = {(const float*)d_in[7],  (const float*)d_in[14], (const float*)d_in[21]};
  const float* Wev[3]  = {(const float*)d_in[8],  (const float*)d_in[15], (const float*)d_in[22]};
  const float* attv[3] = {(const float*)d_in[9],  (const float*)d_in[16], (const float*)d_in[23]};
  const float* bias[3] = {(const float*)d_in[10], (const float*)d_in[17], (const float*)d_in[24]};

  // ---- workspace layout (floats) ----
  float* ws = (float*)d_ws;
  float* xl     = ws;                          // N*512
  float* xr     = xl + (size_t)N * 512;        // N*512
  float* ea_csr = xr + (size_t)N * 512;        // E*16
  float* h      = ea_csr + (size_t)E * 16;     // N*256 (aliased: build ints / hsumA,B)
  int* kptr     = (int*)(h + (size_t)N * 256); // NBINS+1
  int* csr_src  = kptr + (NBINS + 1);          // E
  int* bsum     = csr_src + E;                 // <=257
  int* gstart   = bsum + 257;                  // 64
  int* gend     = gstart + 64;                 // 64
  // build-time temps aliased inside h (dead before h is first written):
  int* kcnt    = (int*)h;                      // NBINS
  int* kfill   = kcnt + NBINS;                 // NBINS
  // layer-2 head-pair partial sums aliased inside h (h dead after L2 GEMMs):
  float* hsumA = h;                            // N*128
  float* hsumB = h + (size_t)N * 128;          // N*128
  (void)n_in; (void)out_size; (void)ws_size;

  const int edgeBlocks = (E + 255) / 256;
  const int scanBlocks = (NBINS + 1023) / 1024;  // 157
  const int gatBlocks = (N + 3) / 4;  // 4 waves/block, wave-per-dst
  const int nb32 = N / 32;  // 625
  const int nb16 = N / 16;  // 1250

  // ---- bucketed CSR build + graph bounds ----
  hipMemsetAsync(kcnt, 0, (size_t)2 * NBINS * sizeof(int), stream);  // kcnt+kfill
  hipMemsetAsync(gstart, 0x7f, 64 * sizeof(int), stream);            // ~INT_MAX
  hipMemsetAsync(gend, 0, 64 * sizeof(int), stream);
  hist_b<<<edgeBlocks, 256, 0, stream>>>(ei, kcnt, batch, gstart, gend, E, N, bdiv);
  blk_scan<<<scanBlocks, 1024, 0, stream>>>(kcnt, kptr + 1, bsum, NBINS);
  scan_bsum<<<1, 256, 0, stream>>>(bsum, scanBlocks);
  add_off<<<(NBINS + 255) / 256, 256, 0, stream>>>(kptr, bsum, NBINS);
  csr_fill_b<<<edgeBlocks, 256, 0, stream>>>(ei, kptr, kfill, csr_src, ea, ea_csr, E, bdiv);

  // ================= layer 0 (K=128 -> hc=256, concat) =================
  node_gemm2<128, 256, 32><<<2 * nb32, 256, 0, stream>>>(
      x, Wl[0], blv[0], xl, Wr[0], brv[0], xr, nb32);
  fused_gat<256, 0><<<gatBlocks, 256, 0, stream>>>(
      xl, xr, ea_csr, Wev[0], attv[0], bias[0], kptr, csr_src, h, nullptr, N);

  // ================= layer 1 (K=256 -> hc=256, concat) =================
  node_gemm2<256, 256, 32><<<2 * nb32, 256, 0, stream>>>(
      h, Wl[1], blv[1], xl, Wr[1], brv[1], xr, nb32);
  fused_gat<256, 0><<<gatBlocks, 256, 0, stream>>>(
      xl, xr, ea_csr, Wev[1], attv[1], bias[1], kptr, csr_src, h, nullptr, N);

  // ================= layer 2 (K=256 -> hc=512, mean over heads) =================
  node_gemm2<256, 512, 16><<<2 * nb16, 256, 0, stream>>>(
      h, Wl[2], blv[2], xl, Wr[2], brv[2], xr, nb16);
  fused_gat<512, 1><<<2 * gatBlocks, 256, 0, stream>>>(
      xl, xr, ea_csr, Wev[2], attv[2], bias[2], kptr, csr_src, hsumA, hsumB, N);

  // ================= pooling (mean-over-heads + bias fused, no atomics) ==========
  pool_graph<<<64, 256, 0, stream>>>(hsumA, hsumB, bias[2], gstart, gend, (float*)d_out);
}